// Round 2
// baseline (688.970 us; speedup 1.0000x reference)
//
#include <hip/hip_runtime.h>
#include <hip/hip_bf16.h>
#include <cstdint>

#define NNODE 256
#define NBT   96
#define HIDD  64
#define NHEAD 4

// round-to-nearest-even pack of two f32 into bf16x2 (lo=a, hi=b)
__device__ __forceinline__ unsigned pack_bf16x2(float a, float b) {
  unsigned ua = __float_as_uint(a);
  unsigned ub = __float_as_uint(b);
  unsigned ra = (ua + 0x7FFFu + ((ua >> 16) & 1u)) >> 16;
  unsigned rb = ((ub + 0x7FFFu + ((ub >> 16) & 1u)) >> 16) << 16;
  return ra | rb;
}

// ---------------------------------------------------------------------------
// Kernel 1: bit-pack adjacency transposed: mb[bt][j][w] bit b = (adj[bt][32w+b][j] != 0)
// ---------------------------------------------------------------------------
__global__ __launch_bounds__(256) void pack_mask_kernel(const int* __restrict__ adj,
                                                        unsigned* __restrict__ mb) {
  const int bt = blockIdx.x, j = threadIdx.x;
  const int* a = adj + (size_t)bt * NNODE * NNODE;
  unsigned* o = mb + ((size_t)bt * NNODE + j) * 8;
  for (int w = 0; w < 8; ++w) {
    unsigned v = 0;
    for (int b = 0; b < 32; ++b) {
      int i = w * 32 + b;
      v |= (a[(size_t)i * NNODE + j] != 0 ? 1u : 0u) << b;
    }
    o[w] = v;
  }
}

// ---------------------------------------------------------------------------
// Kernel 2: small embedding chains.
//   blocks 0..95   : t = (te@Wt+bt)@Wfc+bfc ; tW[row] = t@Wout[64:128] + bout
//   blocks 96..351 : s,p chains; sp = concat(s,p)@Wout+bout ; spW[n] = sp@Wout[64:128]
// ---------------------------------------------------------------------------
__global__ __launch_bounds__(64) void embed_kernel(
    const float* __restrict__ te, const float* __restrict__ se, const float* __restrict__ pe,
    const float* __restrict__ Wt, const float* __restrict__ bt_,
    const float* __restrict__ Ws, const float* __restrict__ bs_,
    const float* __restrict__ Wp, const float* __restrict__ bp_,
    const float* __restrict__ Wfc, const float* __restrict__ bfc,
    const float* __restrict__ Wout, const float* __restrict__ bout,
    float* __restrict__ tW, float* __restrict__ spW) {
  const int j = threadIdx.x;
  __shared__ float A[64], Bv[64], C[64], D[64];
  const int blk = blockIdx.x;
  if (blk < NBT) {
    const int row = blk;
    float h = bt_[j];
    for (int k = 0; k < 32; ++k) h += te[row * 32 + k] * Wt[k * 64 + j];
    A[j] = h;
    __syncthreads();
    float tv = bfc[j];
    for (int k = 0; k < 64; ++k) tv += A[k] * Wfc[k * 64 + j];
    Bv[j] = tv;
    __syncthreads();
    float tw = bout[j];
    for (int d = 0; d < 64; ++d) tw += Bv[d] * Wout[(64 + d) * 64 + j];
    tW[row * 64 + j] = tw;
  } else {
    const int n = blk - NBT;
    float sh = bs_[j], ph = bp_[j];
    for (int k = 0; k < 32; ++k) {
      sh += se[n * 32 + k] * Ws[k * 64 + j];
      ph += pe[n * 32 + k] * Wp[k * 64 + j];
    }
    A[j] = sh; Bv[j] = ph;
    __syncthreads();
    float sv = bfc[j], pv = bfc[j];
    for (int k = 0; k < 64; ++k) {
      sv += A[k] * Wfc[k * 64 + j];
      pv += Bv[k] * Wfc[k * 64 + j];
    }
    C[j] = sv; D[j] = pv;
    __syncthreads();
    float spv = bout[j];
    for (int k = 0; k < 64; ++k)
      spv += C[k] * Wout[k * 64 + j] + D[k] * Wout[(64 + k) * 64 + j];
    __syncthreads();            // everyone done reading A
    A[j] = spv;
    __syncthreads();
    float spw = 0.f;
    for (int d = 0; d < 64; ++d) spw += A[d] * Wout[(64 + d) * 64 + j];
    spW[n * 64 + j] = spw;
  }
}

// ---------------------------------------------------------------------------
// Kernel 3: GAT layer 1, one block per (head, bt). 256 threads = 1 node each.
//   hp = x@W1[:,h*64:+64] (regs) -> es/ed -> hp to LDS (bf16) -> masked softmax
//   aggregation over sources -> h = elu(agg + b1)
// ---------------------------------------------------------------------------
__global__ __launch_bounds__(256) void gat1_kernel(
    const float* __restrict__ x, const unsigned* __restrict__ mb,
    const float* __restrict__ W1, const float* __restrict__ a1s,
    const float* __restrict__ a1d, const float* __restrict__ b1,
    float* __restrict__ hout) {
  const int head = blockIdx.x, bt = blockIdx.y, tid = threadIdx.x;
  __shared__ union SMem {
    struct { float xt[NNODE][33]; float wt[32][64]; } p1;   // 33792 + 8192
    struct { unsigned hp[NNODE][36]; float es[NNODE]; } p2; // 36864 + 1024
  } sm;

  float acc[64];
#pragma unroll
  for (int j = 0; j < 64; ++j) acc[j] = 0.f;

  const float* xrow = x + ((size_t)bt * NNODE + tid) * 64;
  for (int chunk = 0; chunk < 2; ++chunk) {
    const int k0 = chunk * 32;
#pragma unroll
    for (int q = 0; q < 8; ++q) {
      float4 v = *reinterpret_cast<const float4*>(xrow + k0 + q * 4);
      sm.p1.xt[tid][q * 4 + 0] = v.x; sm.p1.xt[tid][q * 4 + 1] = v.y;
      sm.p1.xt[tid][q * 4 + 2] = v.z; sm.p1.xt[tid][q * 4 + 3] = v.w;
    }
#pragma unroll
    for (int i = 0; i < 8; ++i) {
      int l = tid + i * 256, r = l >> 6, c = l & 63;
      sm.p1.wt[r][c] = W1[(size_t)(k0 + r) * 256 + head * 64 + c];
    }
    __syncthreads();
#pragma unroll 4
    for (int kk = 0; kk < 32; ++kk) {
      float xv = sm.p1.xt[tid][kk];
#pragma unroll
      for (int q = 0; q < 16; ++q) {
        float4 wv = *reinterpret_cast<const float4*>(&sm.p1.wt[kk][q * 4]);
        acc[q * 4 + 0] += xv * wv.x; acc[q * 4 + 1] += xv * wv.y;
        acc[q * 4 + 2] += xv * wv.z; acc[q * 4 + 3] += xv * wv.w;
      }
    }
    __syncthreads();
  }

  // attention logits
  float es = 0.f, ed = 0.f;
#pragma unroll
  for (int d = 0; d < 64; ++d) {
    es += acc[d] * a1s[head * 64 + d];
    ed += acc[d] * a1d[head * 64 + d];
  }

  // restage hp (bf16) + es into LDS (safe: sync'd after last GEMM read)
#pragma unroll
  for (int p = 0; p < 32; ++p)
    sm.p2.hp[tid][p] = pack_bf16x2(acc[2 * p], acc[2 * p + 1]);
  sm.p2.es[tid] = es;
  __syncthreads();

  unsigned mbits[8];
  const unsigned* mrow = mb + ((size_t)bt * NNODE + tid) * 8;
#pragma unroll
  for (int w = 0; w < 8; ++w) mbits[w] = mrow[w];

  float agg[64];
#pragma unroll
  for (int j = 0; j < 64; ++j) agg[j] = 0.f;
  float denom = 0.f;

#pragma unroll
  for (int w = 0; w < 8; ++w) {           // static index into mbits
    const unsigned bits = mbits[w];
    for (int b = 0; b < 32; ++b) {
      const int i = w * 32 + b;
      float sc = sm.p2.es[i] + ed;
      float l = sc > 0.f ? sc : 0.2f * sc;
      float wgt = ((bits >> b) & 1u) ? __expf(l) : 0.f;
      denom += wgt;
#pragma unroll
      for (int q = 0; q < 8; ++q) {
        uint4 u = *reinterpret_cast<const uint4*>(&sm.p2.hp[i][q * 4]);
        agg[q * 8 + 0] += wgt * __uint_as_float(u.x << 16);
        agg[q * 8 + 1] += wgt * __uint_as_float(u.x & 0xFFFF0000u);
        agg[q * 8 + 2] += wgt * __uint_as_float(u.y << 16);
        agg[q * 8 + 3] += wgt * __uint_as_float(u.y & 0xFFFF0000u);
        agg[q * 8 + 4] += wgt * __uint_as_float(u.z << 16);
        agg[q * 8 + 5] += wgt * __uint_as_float(u.z & 0xFFFF0000u);
        agg[q * 8 + 6] += wgt * __uint_as_float(u.w << 16);
        agg[q * 8 + 7] += wgt * __uint_as_float(u.w & 0xFFFF0000u);
      }
    }
  }

  const float inv = 1.f / fmaxf(denom, 1e-30f);
  float* hrow = hout + (((size_t)bt * NNODE + tid) * 256) + head * 64;
#pragma unroll
  for (int q = 0; q < 16; ++q) {
    float4 v;
    float t0 = agg[q * 4 + 0] * inv + b1[head * 64 + q * 4 + 0];
    float t1 = agg[q * 4 + 1] * inv + b1[head * 64 + q * 4 + 1];
    float t2 = agg[q * 4 + 2] * inv + b1[head * 64 + q * 4 + 2];
    float t3 = agg[q * 4 + 3] * inv + b1[head * 64 + q * 4 + 3];
    v.x = t0 > 0.f ? t0 : expm1f(t0);
    v.y = t1 > 0.f ? t1 : expm1f(t1);
    v.z = t2 > 0.f ? t2 : expm1f(t2);
    v.w = t3 > 0.f ? t3 : expm1f(t3);
    *reinterpret_cast<float4*>(hrow + q * 4) = v;
  }
}

// ---------------------------------------------------------------------------
// Kernel 4: GAT layer 2 (1 head) + fused final projection. One block per bt.
//   hp2 = h@W2 (K=256, 8 LDS chunks) -> attention -> od = agg+b2
//   out = od@Wout[0:64] + spW[n] + tW[bt]
// ---------------------------------------------------------------------------
__global__ __launch_bounds__(256) void gat2_kernel(
    const float* __restrict__ h, const unsigned* __restrict__ mb,
    const float* __restrict__ W2, const float* __restrict__ a2s,
    const float* __restrict__ a2d, const float* __restrict__ b2,
    const float* __restrict__ Wout, const float* __restrict__ spW,
    const float* __restrict__ tW, float* __restrict__ out) {
  const int bt = blockIdx.x, tid = threadIdx.x;
  __shared__ union SMem {
    struct { float ht[NNODE][33]; float wt[32][64]; } p1;                     // 41984
    struct { unsigned hp[NNODE][36]; float es[NNODE]; float wo[64][64]; } p2; // 54272
  } sm;

  float acc[64];
#pragma unroll
  for (int j = 0; j < 64; ++j) acc[j] = 0.f;

  const float* hrow = h + ((size_t)bt * NNODE + tid) * 256;
  for (int chunk = 0; chunk < 8; ++chunk) {
    const int k0 = chunk * 32;
#pragma unroll
    for (int q = 0; q < 8; ++q) {
      float4 v = *reinterpret_cast<const float4*>(hrow + k0 + q * 4);
      sm.p1.ht[tid][q * 4 + 0] = v.x; sm.p1.ht[tid][q * 4 + 1] = v.y;
      sm.p1.ht[tid][q * 4 + 2] = v.z; sm.p1.ht[tid][q * 4 + 3] = v.w;
    }
#pragma unroll
    for (int i = 0; i < 8; ++i) {
      int l = tid + i * 256, r = l >> 6, c = l & 63;
      sm.p1.wt[r][c] = W2[(size_t)(k0 + r) * 64 + c];
    }
    __syncthreads();
#pragma unroll 4
    for (int kk = 0; kk < 32; ++kk) {
      float hv = sm.p1.ht[tid][kk];
#pragma unroll
      for (int q = 0; q < 16; ++q) {
        float4 wv = *reinterpret_cast<const float4*>(&sm.p1.wt[kk][q * 4]);
        acc[q * 4 + 0] += hv * wv.x; acc[q * 4 + 1] += hv * wv.y;
        acc[q * 4 + 2] += hv * wv.z; acc[q * 4 + 3] += hv * wv.w;
      }
    }
    __syncthreads();
  }

  float es = 0.f, ed = 0.f;
#pragma unroll
  for (int d = 0; d < 64; ++d) {
    es += acc[d] * a2s[d];
    ed += acc[d] * a2d[d];
  }

#pragma unroll
  for (int p = 0; p < 32; ++p)
    sm.p2.hp[tid][p] = pack_bf16x2(acc[2 * p], acc[2 * p + 1]);
  sm.p2.es[tid] = es;
  // stage Wout top half for the fused epilogue (disjoint LDS region)
#pragma unroll
  for (int i = 0; i < 16; ++i) {
    int l = tid + i * 256, r = l >> 6, c = l & 63;
    sm.p2.wo[r][c] = Wout[r * 64 + c];
  }
  __syncthreads();

  unsigned mbits[8];
  const unsigned* mrow = mb + ((size_t)bt * NNODE + tid) * 8;
#pragma unroll
  for (int w = 0; w < 8; ++w) mbits[w] = mrow[w];

  float agg[64];
#pragma unroll
  for (int j = 0; j < 64; ++j) agg[j] = 0.f;
  float denom = 0.f;

#pragma unroll
  for (int w = 0; w < 8; ++w) {
    const unsigned bits = mbits[w];
    for (int b = 0; b < 32; ++b) {
      const int i = w * 32 + b;
      float sc = sm.p2.es[i] + ed;
      float l = sc > 0.f ? sc : 0.2f * sc;
      float wgt = ((bits >> b) & 1u) ? __expf(l) : 0.f;
      denom += wgt;
#pragma unroll
      for (int q = 0; q < 8; ++q) {
        uint4 u = *reinterpret_cast<const uint4*>(&sm.p2.hp[i][q * 4]);
        agg[q * 8 + 0] += wgt * __uint_as_float(u.x << 16);
        agg[q * 8 + 1] += wgt * __uint_as_float(u.x & 0xFFFF0000u);
        agg[q * 8 + 2] += wgt * __uint_as_float(u.y << 16);
        agg[q * 8 + 3] += wgt * __uint_as_float(u.y & 0xFFFF0000u);
        agg[q * 8 + 4] += wgt * __uint_as_float(u.z << 16);
        agg[q * 8 + 5] += wgt * __uint_as_float(u.z & 0xFFFF0000u);
        agg[q * 8 + 6] += wgt * __uint_as_float(u.w << 16);
        agg[q * 8 + 7] += wgt * __uint_as_float(u.w & 0xFFFF0000u);
      }
    }
  }

  const float inv = 1.f / fmaxf(denom, 1e-30f);
#pragma unroll
  for (int d = 0; d < 64; ++d) acc[d] = agg[d] * inv + b2[d];  // od

  // fused final: out = od @ Wout[0:64] + spW[n] + tW[bt]
  float acc2[64];
#pragma unroll
  for (int q = 0; q < 16; ++q) {
    float4 a = *reinterpret_cast<const float4*>(spW + (size_t)tid * 64 + q * 4);
    float4 c = *reinterpret_cast<const float4*>(tW + (size_t)bt * 64 + q * 4);
    acc2[q * 4 + 0] = a.x + c.x; acc2[q * 4 + 1] = a.y + c.y;
    acc2[q * 4 + 2] = a.z + c.z; acc2[q * 4 + 3] = a.w + c.w;
  }
#pragma unroll
  for (int d = 0; d < 64; ++d) {
    const float o = acc[d];
#pragma unroll
    for (int q = 0; q < 16; ++q) {
      float4 wv = *reinterpret_cast<const float4*>(&sm.p2.wo[d][q * 4]);
      acc2[q * 4 + 0] += o * wv.x; acc2[q * 4 + 1] += o * wv.y;
      acc2[q * 4 + 2] += o * wv.z; acc2[q * 4 + 3] += o * wv.w;
    }
  }
  float* orow = out + ((size_t)bt * NNODE + tid) * 64;
#pragma unroll
  for (int q = 0; q < 16; ++q) {
    float4 v;
    v.x = acc2[q * 4 + 0]; v.y = acc2[q * 4 + 1];
    v.z = acc2[q * 4 + 2]; v.w = acc2[q * 4 + 3];
    *reinterpret_cast<float4*>(orow + q * 4) = v;
  }
}

// ---------------------------------------------------------------------------
extern "C" void kernel_launch(void* const* d_in, const int* in_sizes, int n_in,
                              void* d_out, int out_size, void* d_ws, size_t ws_size,
                              hipStream_t stream) {
  const float* x    = (const float*)d_in[0];
  const int*   adj  = (const int*)d_in[1];
  const float* te   = (const float*)d_in[2];
  const float* se   = (const float*)d_in[3];
  const float* pe   = (const float*)d_in[4];
  const float* Wt   = (const float*)d_in[5];
  const float* bt_  = (const float*)d_in[6];
  const float* Ws   = (const float*)d_in[7];
  const float* bs_  = (const float*)d_in[8];
  const float* Wp   = (const float*)d_in[9];
  const float* bp_  = (const float*)d_in[10];
  const float* Wfc  = (const float*)d_in[11];
  const float* bfc  = (const float*)d_in[12];
  const float* Wout = (const float*)d_in[13];
  const float* bout = (const float*)d_in[14];
  const float* W1   = (const float*)d_in[15];
  const float* b1   = (const float*)d_in[16];
  const float* a1s  = (const float*)d_in[17];
  const float* a1d  = (const float*)d_in[18];
  const float* W2   = (const float*)d_in[19];
  const float* b2   = (const float*)d_in[20];
  const float* a2s  = (const float*)d_in[21];
  const float* a2d  = (const float*)d_in[22];

  // workspace layout
  char* ws = (char*)d_ws;
  unsigned* mb = (unsigned*)ws;                       // 96*256*8 u32  = 786432 B
  float* tW    = (float*)(ws + 786432);               // 96*64 f32     = 24576 B
  float* spW   = (float*)(ws + 786432 + 24576);       // 256*64 f32    = 65536 B
  float* h     = (float*)(ws + 786432 + 24576 + 65536); // 96*256*256 f32 = 25165824 B

  pack_mask_kernel<<<NBT, 256, 0, stream>>>(adj, mb);
  embed_kernel<<<NBT + NNODE, 64, 0, stream>>>(te, se, pe, Wt, bt_, Ws, bs_,
                                               Wp, bp_, Wfc, bfc, Wout, bout, tW, spW);
  gat1_kernel<<<dim3(NHEAD, NBT), 256, 0, stream>>>(x, mb, W1, a1s, a1d, b1, h);
  gat2_kernel<<<NBT, 256, 0, stream>>>(h, mb, W2, a2s, a2d, b2, Wout, spW, tW,
                                       (float*)d_out);
}

// Round 3
// 346.698 us; speedup vs baseline: 1.9872x; 1.9872x over previous
//
#include <hip/hip_runtime.h>
#include <hip/hip_bf16.h>
#include <cstdint>

#define NNODE 256
#define NBT   96

// round-to-nearest-even pack of two f32 into bf16x2 (lo=a, hi=b)
__device__ __forceinline__ unsigned pack_bf16x2(float a, float b) {
  unsigned ua = __float_as_uint(a);
  unsigned ub = __float_as_uint(b);
  unsigned ra = (ua + 0x7FFFu + ((ua >> 16) & 1u)) >> 16;
  unsigned rb = ((ub + 0x7FFFu + ((ub >> 16) & 1u)) >> 16) << 16;
  return ra | rb;
}
__device__ __forceinline__ float blo(unsigned u) { return __uint_as_float(u << 16); }
__device__ __forceinline__ float bhi(unsigned u) { return __uint_as_float(u & 0xFFFF0000u); }

// ---------------------------------------------------------------------------
// Kernel 1: bit-pack adjacency transposed. grid (96, 8), 256 thr.
// mb[bt][j][w] bit b = (adj[bt][32w+b][j] != 0)
// ---------------------------------------------------------------------------
__global__ __launch_bounds__(256) void pack_mask_kernel(const int* __restrict__ adj,
                                                        unsigned* __restrict__ mb) {
  const int bt = blockIdx.x, w = blockIdx.y, j = threadIdx.x;
  const int* a = adj + (size_t)bt * NNODE * NNODE + (size_t)w * 32 * NNODE;
  unsigned v = 0;
#pragma unroll
  for (int b = 0; b < 32; ++b)
    v |= (a[b * NNODE + j] != 0 ? 1u : 0u) << b;
  mb[((size_t)bt * NNODE + j) * 8 + w] = v;
}

// ---------------------------------------------------------------------------
// Kernel 2: small embedding chains (unchanged from round 0 — verified).
// ---------------------------------------------------------------------------
__global__ __launch_bounds__(64) void embed_kernel(
    const float* __restrict__ te, const float* __restrict__ se, const float* __restrict__ pe,
    const float* __restrict__ Wt, const float* __restrict__ bt_,
    const float* __restrict__ Ws, const float* __restrict__ bs_,
    const float* __restrict__ Wp, const float* __restrict__ bp_,
    const float* __restrict__ Wfc, const float* __restrict__ bfc,
    const float* __restrict__ Wout, const float* __restrict__ bout,
    float* __restrict__ tW, float* __restrict__ spW) {
  const int j = threadIdx.x;
  __shared__ float A[64], Bv[64], C[64], D[64];
  const int blk = blockIdx.x;
  if (blk < NBT) {
    const int row = blk;
    float h = bt_[j];
    for (int k = 0; k < 32; ++k) h += te[row * 32 + k] * Wt[k * 64 + j];
    A[j] = h;
    __syncthreads();
    float tv = bfc[j];
    for (int k = 0; k < 64; ++k) tv += A[k] * Wfc[k * 64 + j];
    Bv[j] = tv;
    __syncthreads();
    float tw = bout[j];
    for (int d = 0; d < 64; ++d) tw += Bv[d] * Wout[(64 + d) * 64 + j];
    tW[row * 64 + j] = tw;
  } else {
    const int n = blk - NBT;
    float sh = bs_[j], ph = bp_[j];
    for (int k = 0; k < 32; ++k) {
      sh += se[n * 32 + k] * Ws[k * 64 + j];
      ph += pe[n * 32 + k] * Wp[k * 64 + j];
    }
    A[j] = sh; Bv[j] = ph;
    __syncthreads();
    float sv = bfc[j], pv = bfc[j];
    for (int k = 0; k < 64; ++k) {
      sv += A[k] * Wfc[k * 64 + j];
      pv += Bv[k] * Wfc[k * 64 + j];
    }
    C[j] = sv; D[j] = pv;
    __syncthreads();
    float spv = bout[j];
    for (int k = 0; k < 64; ++k)
      spv += C[k] * Wout[k * 64 + j] + D[k] * Wout[(64 + k) * 64 + j];
    __syncthreads();
    A[j] = spv;
    __syncthreads();
    float spw = 0.f;
    for (int d = 0; d < 64; ++d) spw += A[d] * Wout[(64 + d) * 64 + j];
    spW[n * 64 + j] = spw;
  }
}

// ---------------------------------------------------------------------------
// Kernel 3: feat1 — hp1 = x @ W1[:, head*64:+64], bf16 out. grid (4, 96), 256 thr.
// hp1 layout: [bt][n][256] bf16 (uint pairs), dim hd = head*64+d.
// ---------------------------------------------------------------------------
__global__ __launch_bounds__(256) void feat1_kernel(
    const float* __restrict__ x, const float* __restrict__ W1,
    unsigned* __restrict__ hp1) {
  const int head = blockIdx.x, bt = blockIdx.y, tid = threadIdx.x;
  __shared__ float xt[NNODE][33];
  __shared__ float wt[32][64];

  float acc[64];
#pragma unroll
  for (int j = 0; j < 64; ++j) acc[j] = 0.f;

  const float* xrow = x + ((size_t)bt * NNODE + tid) * 64;
  for (int chunk = 0; chunk < 2; ++chunk) {
    const int k0 = chunk * 32;
#pragma unroll
    for (int q = 0; q < 8; ++q) {
      float4 v = *reinterpret_cast<const float4*>(xrow + k0 + q * 4);
      xt[tid][q * 4 + 0] = v.x; xt[tid][q * 4 + 1] = v.y;
      xt[tid][q * 4 + 2] = v.z; xt[tid][q * 4 + 3] = v.w;
    }
#pragma unroll
    for (int i = 0; i < 8; ++i) {
      int l = tid + i * 256, r = l >> 6, c = l & 63;
      wt[r][c] = W1[(size_t)(k0 + r) * 256 + head * 64 + c];
    }
    __syncthreads();
#pragma unroll 4
    for (int kk = 0; kk < 32; ++kk) {
      float xv = xt[tid][kk];
#pragma unroll
      for (int q = 0; q < 16; ++q) {
        float4 wv = *reinterpret_cast<const float4*>(&wt[kk][q * 4]);
        acc[q * 4 + 0] += xv * wv.x; acc[q * 4 + 1] += xv * wv.y;
        acc[q * 4 + 2] += xv * wv.z; acc[q * 4 + 3] += xv * wv.w;
      }
    }
    __syncthreads();
  }

  unsigned* orow = hp1 + ((size_t)bt * NNODE + tid) * 128 + head * 32;
#pragma unroll
  for (int q = 0; q < 8; ++q) {
    uint4 u;
    u.x = pack_bf16x2(acc[q * 8 + 0], acc[q * 8 + 1]);
    u.y = pack_bf16x2(acc[q * 8 + 2], acc[q * 8 + 3]);
    u.z = pack_bf16x2(acc[q * 8 + 4], acc[q * 8 + 5]);
    u.w = pack_bf16x2(acc[q * 8 + 6], acc[q * 8 + 7]);
    *reinterpret_cast<uint4*>(orow + q * 4) = u;
  }
}

// ---------------------------------------------------------------------------
// Kernel 4: agg1 — masked softmax aggregation + elu, layer 1.
// grid (96, 4, 2): (bt, head, z-half of dims). thread = target node, 32 dims.
// Writes h[bt][n][256] bf16 (same layout as hp1, separate buffer).
// ---------------------------------------------------------------------------
__global__ __launch_bounds__(256, 2) void agg1_kernel(
    const unsigned* __restrict__ hp1, const unsigned* __restrict__ mb,
    const float* __restrict__ a1s, const float* __restrict__ a1d,
    const float* __restrict__ b1, unsigned* __restrict__ hgl) {
  const int bt = blockIdx.x, head = blockIdx.y, z = blockIdx.z, tid = threadIdx.x;
  __shared__ unsigned hp[NNODE][36];
  __shared__ float es[NNODE];

  // stage this node's hp1 slice; compute es/ed from bf16 values
  const unsigned* grow = hp1 + ((size_t)bt * NNODE + tid) * 128 + head * 32;
  uint4 r[8];
#pragma unroll
  for (int q = 0; q < 8; ++q) r[q] = reinterpret_cast<const uint4*>(grow)[q];
#pragma unroll
  for (int q = 0; q < 8; ++q) *reinterpret_cast<uint4*>(&hp[tid][q * 4]) = r[q];

  const float* as = a1s + head * 64;
  const float* ad = a1d + head * 64;
  float esv = 0.f, edv = 0.f;
#pragma unroll
  for (int q = 0; q < 8; ++q) {
    float v0 = blo(r[q].x), v1 = bhi(r[q].x), v2 = blo(r[q].y), v3 = bhi(r[q].y);
    float v4 = blo(r[q].z), v5 = bhi(r[q].z), v6 = blo(r[q].w), v7 = bhi(r[q].w);
    esv += v0 * as[q * 8 + 0] + v1 * as[q * 8 + 1] + v2 * as[q * 8 + 2] + v3 * as[q * 8 + 3]
         + v4 * as[q * 8 + 4] + v5 * as[q * 8 + 5] + v6 * as[q * 8 + 6] + v7 * as[q * 8 + 7];
    edv += v0 * ad[q * 8 + 0] + v1 * ad[q * 8 + 1] + v2 * ad[q * 8 + 2] + v3 * ad[q * 8 + 3]
         + v4 * ad[q * 8 + 4] + v5 * ad[q * 8 + 5] + v6 * ad[q * 8 + 6] + v7 * ad[q * 8 + 7];
  }
  es[tid] = esv;
  __syncthreads();

  unsigned mbits[8];
  const unsigned* mrow = mb + ((size_t)bt * NNODE + tid) * 8;
#pragma unroll
  for (int w = 0; w < 8; ++w) mbits[w] = mrow[w];

  float agg[32];
#pragma unroll
  for (int m = 0; m < 32; ++m) agg[m] = 0.f;
  float denom = 0.f;

#pragma unroll
  for (int w = 0; w < 8; ++w) {
    const unsigned bits = mbits[w];
    for (int b = 0; b < 32; ++b) {
      const int i = w * 32 + b;
      float sc = es[i] + edv;
      float l = sc > 0.f ? sc : 0.2f * sc;
      float wgt = ((bits >> b) & 1u) ? __expf(l) : 0.f;
      denom += wgt;
#pragma unroll
      for (int q = 0; q < 4; ++q) {
        uint4 u = *reinterpret_cast<const uint4*>(&hp[i][z * 16 + q * 4]);
        agg[q * 8 + 0] += wgt * blo(u.x); agg[q * 8 + 1] += wgt * bhi(u.x);
        agg[q * 8 + 2] += wgt * blo(u.y); agg[q * 8 + 3] += wgt * bhi(u.y);
        agg[q * 8 + 4] += wgt * blo(u.z); agg[q * 8 + 5] += wgt * bhi(u.z);
        agg[q * 8 + 6] += wgt * blo(u.w); agg[q * 8 + 7] += wgt * bhi(u.w);
      }
    }
  }

  const float inv = 1.f / fmaxf(denom, 1e-30f);
  const float* bb = b1 + head * 64 + z * 32;
  unsigned* orow = hgl + ((size_t)bt * NNODE + tid) * 128 + head * 32 + z * 16;
#pragma unroll
  for (int q = 0; q < 4; ++q) {
    float t[8];
#pragma unroll
    for (int m = 0; m < 8; ++m) {
      float v = agg[q * 8 + m] * inv + bb[q * 8 + m];
      t[m] = v > 0.f ? v : expm1f(v);
    }
    uint4 u;
    u.x = pack_bf16x2(t[0], t[1]); u.y = pack_bf16x2(t[2], t[3]);
    u.z = pack_bf16x2(t[4], t[5]); u.w = pack_bf16x2(t[6], t[7]);
    *reinterpret_cast<uint4*>(orow + q * 4) = u;
  }
}

// ---------------------------------------------------------------------------
// Kernel 5: feat2 — hp2 = h @ W2 (K=256), bf16 out. grid (96, 4), 256 thr.
// block (bt, g): nodes g*64..+64; thread = (node nl = tid>>2, part p = tid&3, 16 dims).
// ---------------------------------------------------------------------------
__global__ __launch_bounds__(256, 2) void feat2_kernel(
    const unsigned* __restrict__ hgl, const float* __restrict__ W2,
    unsigned* __restrict__ hp2) {
  const int bt = blockIdx.x, g = blockIdx.y, tid = threadIdx.x;
  __shared__ unsigned ht[64][130];   // 64 nodes x 128 uints (256 bf16), +2 pad
  __shared__ unsigned w2[256][33];   // 256 rows x 32 uints (64 bf16), +1 pad

  const int nl = tid >> 2, p = tid & 3;
  const unsigned* hrow = hgl + ((size_t)bt * NNODE + g * 64 + nl) * 128 + p * 32;
#pragma unroll
  for (int q = 0; q < 8; ++q)
    *reinterpret_cast<uint4*>(&ht[nl][p * 32 + q * 4]) =
        reinterpret_cast<const uint4*>(hrow)[q];
  {
    const float* wr = W2 + (size_t)tid * 64;
#pragma unroll
    for (int q = 0; q < 8; ++q) {
      float4 w0 = reinterpret_cast<const float4*>(wr)[2 * q];
      float4 w1 = reinterpret_cast<const float4*>(wr)[2 * q + 1];
      uint4 u;
      u.x = pack_bf16x2(w0.x, w0.y); u.y = pack_bf16x2(w0.z, w0.w);
      u.z = pack_bf16x2(w1.x, w1.y); u.w = pack_bf16x2(w1.z, w1.w);
      *reinterpret_cast<uint4*>(&w2[tid][q * 4]) = u;
    }
  }
  __syncthreads();

  float acc[16];
#pragma unroll
  for (int m = 0; m < 16; ++m) acc[m] = 0.f;

  for (int kp = 0; kp < 128; ++kp) {
    const unsigned hu = ht[nl][kp];
    const float h0 = blo(hu), h1 = bhi(hu);
    const int k0 = 2 * kp, k1 = 2 * kp + 1;
#pragma unroll
    for (int q = 0; q < 2; ++q) {
      uint4 u0 = *reinterpret_cast<const uint4*>(&w2[k0][p * 8 + q * 4]);
      uint4 u1 = *reinterpret_cast<const uint4*>(&w2[k1][p * 8 + q * 4]);
      acc[q * 8 + 0] += h0 * blo(u0.x) + h1 * blo(u1.x);
      acc[q * 8 + 1] += h0 * bhi(u0.x) + h1 * bhi(u1.x);
      acc[q * 8 + 2] += h0 * blo(u0.y) + h1 * blo(u1.y);
      acc[q * 8 + 3] += h0 * bhi(u0.y) + h1 * bhi(u1.y);
      acc[q * 8 + 4] += h0 * blo(u0.z) + h1 * blo(u1.z);
      acc[q * 8 + 5] += h0 * bhi(u0.z) + h1 * bhi(u1.z);
      acc[q * 8 + 6] += h0 * blo(u0.w) + h1 * blo(u1.w);
      acc[q * 8 + 7] += h0 * bhi(u0.w) + h1 * bhi(u1.w);
    }
  }

  unsigned* orow = hp2 + ((size_t)bt * NNODE + g * 64 + nl) * 32 + p * 8;
  uint4 o0, o1;
  o0.x = pack_bf16x2(acc[0], acc[1]);  o0.y = pack_bf16x2(acc[2], acc[3]);
  o0.z = pack_bf16x2(acc[4], acc[5]);  o0.w = pack_bf16x2(acc[6], acc[7]);
  o1.x = pack_bf16x2(acc[8], acc[9]);  o1.y = pack_bf16x2(acc[10], acc[11]);
  o1.z = pack_bf16x2(acc[12], acc[13]); o1.w = pack_bf16x2(acc[14], acc[15]);
  reinterpret_cast<uint4*>(orow)[0] = o0;
  reinterpret_cast<uint4*>(orow)[1] = o1;
}

// ---------------------------------------------------------------------------
// Kernel 6: agg2 — layer-2 aggregation + fused final projection.
// grid (96, 4): block (bt, jg) = 64 targets; thread = (jl = tid>>2, part p, 16 dims).
// out = (agg/denom + b2) @ Wout[0:64] + spW[j] + tW[bt]
// ---------------------------------------------------------------------------
__global__ __launch_bounds__(256, 2) void agg2_kernel(
    const unsigned* __restrict__ hp2, const unsigned* __restrict__ mb,
    const float* __restrict__ a2s, const float* __restrict__ a2d,
    const float* __restrict__ b2, const float* __restrict__ Wout,
    const float* __restrict__ spW, const float* __restrict__ tW,
    float* __restrict__ out) {
  const int bt = blockIdx.x, jg = blockIdx.y, tid = threadIdx.x;
  __shared__ unsigned hp[NNODE][36];
  __shared__ float es[NNODE], ed[NNODE];
  __shared__ float wo[64][68];
  __shared__ float od[64][68];

  // stage hp2 row tid + es/ed for node tid
  const unsigned* grow = hp2 + ((size_t)bt * NNODE + tid) * 32;
  uint4 r[8];
#pragma unroll
  for (int q = 0; q < 8; ++q) r[q] = reinterpret_cast<const uint4*>(grow)[q];
#pragma unroll
  for (int q = 0; q < 8; ++q) *reinterpret_cast<uint4*>(&hp[tid][q * 4]) = r[q];
  float esv = 0.f, edv = 0.f;
#pragma unroll
  for (int q = 0; q < 8; ++q) {
    float v0 = blo(r[q].x), v1 = bhi(r[q].x), v2 = blo(r[q].y), v3 = bhi(r[q].y);
    float v4 = blo(r[q].z), v5 = bhi(r[q].z), v6 = blo(r[q].w), v7 = bhi(r[q].w);
    esv += v0 * a2s[q * 8 + 0] + v1 * a2s[q * 8 + 1] + v2 * a2s[q * 8 + 2] + v3 * a2s[q * 8 + 3]
         + v4 * a2s[q * 8 + 4] + v5 * a2s[q * 8 + 5] + v6 * a2s[q * 8 + 6] + v7 * a2s[q * 8 + 7];
    edv += v0 * a2d[q * 8 + 0] + v1 * a2d[q * 8 + 1] + v2 * a2d[q * 8 + 2] + v3 * a2d[q * 8 + 3]
         + v4 * a2d[q * 8 + 4] + v5 * a2d[q * 8 + 5] + v6 * a2d[q * 8 + 6] + v7 * a2d[q * 8 + 7];
  }
  es[tid] = esv; ed[tid] = edv;
  {
    const int d = tid >> 2, c0 = (tid & 3) * 16;
#pragma unroll
    for (int q = 0; q < 4; ++q)
      *reinterpret_cast<float4*>(&wo[d][c0 + q * 4]) =
          *reinterpret_cast<const float4*>(Wout + (size_t)d * 64 + c0 + q * 4);
  }
  __syncthreads();

  const int jl = tid >> 2, p = tid & 3, j = jg * 64 + jl, d0 = p * 16;
  const float edj = ed[j];

  unsigned mbits[8];
  const unsigned* mrow = mb + ((size_t)bt * NNODE + j) * 8;
#pragma unroll
  for (int w = 0; w < 8; ++w) mbits[w] = mrow[w];

  float agg[16];
#pragma unroll
  for (int m = 0; m < 16; ++m) agg[m] = 0.f;
  float denom = 0.f;

#pragma unroll
  for (int w = 0; w < 8; ++w) {
    const unsigned bits = mbits[w];
    for (int b = 0; b < 32; ++b) {
      const int i = w * 32 + b;
      float sc = es[i] + edj;
      float l = sc > 0.f ? sc : 0.2f * sc;
      float wgt = ((bits >> b) & 1u) ? __expf(l) : 0.f;
      denom += wgt;
#pragma unroll
      for (int q = 0; q < 2; ++q) {
        uint4 u = *reinterpret_cast<const uint4*>(&hp[i][p * 8 + q * 4]);
        agg[q * 8 + 0] += wgt * blo(u.x); agg[q * 8 + 1] += wgt * bhi(u.x);
        agg[q * 8 + 2] += wgt * blo(u.y); agg[q * 8 + 3] += wgt * bhi(u.y);
        agg[q * 8 + 4] += wgt * blo(u.z); agg[q * 8 + 5] += wgt * bhi(u.z);
        agg[q * 8 + 6] += wgt * blo(u.w); agg[q * 8 + 7] += wgt * bhi(u.w);
      }
    }
  }

  const float inv = 1.f / fmaxf(denom, 1e-30f);
#pragma unroll
  for (int m = 0; m < 16; ++m)
    od[jl][d0 + m] = agg[m] * inv + b2[d0 + m];
  __syncthreads();

  float acc2[16];
#pragma unroll
  for (int q = 0; q < 4; ++q) {
    float4 sv = *reinterpret_cast<const float4*>(spW + (size_t)j * 64 + d0 + q * 4);
    float4 tv = *reinterpret_cast<const float4*>(tW + (size_t)bt * 64 + d0 + q * 4);
    acc2[q * 4 + 0] = sv.x + tv.x; acc2[q * 4 + 1] = sv.y + tv.y;
    acc2[q * 4 + 2] = sv.z + tv.z; acc2[q * 4 + 3] = sv.w + tv.w;
  }
#pragma unroll 8
  for (int d = 0; d < 64; ++d) {
    const float o = od[jl][d];
#pragma unroll
    for (int q = 0; q < 4; ++q) {
      float4 wv = *reinterpret_cast<const float4*>(&wo[d][d0 + q * 4]);
      acc2[q * 4 + 0] += o * wv.x; acc2[q * 4 + 1] += o * wv.y;
      acc2[q * 4 + 2] += o * wv.z; acc2[q * 4 + 3] += o * wv.w;
    }
  }
  float* orow = out + ((size_t)bt * NNODE + j) * 64 + d0;
#pragma unroll
  for (int q = 0; q < 4; ++q) {
    float4 v;
    v.x = acc2[q * 4 + 0]; v.y = acc2[q * 4 + 1];
    v.z = acc2[q * 4 + 2]; v.w = acc2[q * 4 + 3];
    *reinterpret_cast<float4*>(orow + q * 4) = v;
  }
}

// ---------------------------------------------------------------------------
extern "C" void kernel_launch(void* const* d_in, const int* in_sizes, int n_in,
                              void* d_out, int out_size, void* d_ws, size_t ws_size,
                              hipStream_t stream) {
  const float* x    = (const float*)d_in[0];
  const int*   adj  = (const int*)d_in[1];
  const float* te   = (const float*)d_in[2];
  const float* se   = (const float*)d_in[3];
  const float* pe   = (const float*)d_in[4];
  const float* Wt   = (const float*)d_in[5];
  const float* bt_  = (const float*)d_in[6];
  const float* Ws   = (const float*)d_in[7];
  const float* bs_  = (const float*)d_in[8];
  const float* Wp   = (const float*)d_in[9];
  const float* bp_  = (const float*)d_in[10];
  const float* Wfc  = (const float*)d_in[11];
  const float* bfc  = (const float*)d_in[12];
  const float* Wout = (const float*)d_in[13];
  const float* bout = (const float*)d_in[14];
  const float* W1   = (const float*)d_in[15];
  const float* b1   = (const float*)d_in[16];
  const float* a1s  = (const float*)d_in[17];
  const float* a1d  = (const float*)d_in[18];
  const float* W2   = (const float*)d_in[19];
  const float* b2   = (const float*)d_in[20];
  const float* a2s  = (const float*)d_in[21];
  const float* a2d  = (const float*)d_in[22];

  // workspace layout (total 26,042,368 B == round-0 footprint, proven to fit)
  char* ws = (char*)d_ws;
  unsigned* mb  = (unsigned*)ws;                       // 96*256*8 u32   = 786432 B
  float* tW     = (float*)(ws + 786432);               // 96*64 f32      = 24576 B
  float* spW    = (float*)(ws + 811008);               // 256*64 f32     = 65536 B
  unsigned* hp1 = (unsigned*)(ws + 876544);            // 96*256*128 u32 = 12582912 B
  unsigned* hgl = (unsigned*)(ws + 876544 + 12582912); // 96*256*128 u32 = 12582912 B
  unsigned* hp2 = hp1;  // overlays hp1: stream order guarantees A1 done before F2

  pack_mask_kernel<<<dim3(NBT, 8), 256, 0, stream>>>(adj, mb);
  embed_kernel<<<NBT + NNODE, 64, 0, stream>>>(te, se, pe, Wt, bt_, Ws, bs_,
                                               Wp, bp_, Wfc, bfc, Wout, bout, tW, spW);
  feat1_kernel<<<dim3(4, NBT), 256, 0, stream>>>(x, W1, hp1);
  agg1_kernel<<<dim3(NBT, 4, 2), 256, 0, stream>>>(hp1, mb, a1s, a1d, b1, hgl);
  feat2_kernel<<<dim3(NBT, 4), 256, 0, stream>>>(hgl, W2, hp2);
  agg2_kernel<<<dim3(NBT, 4), 256, 0, stream>>>(hp2, mb, a2s, a2d, b2, Wout,
                                                spW, tW, (float*)d_out);
}

// Round 5
// 250.260 us; speedup vs baseline: 2.7530x; 1.3854x over previous
//
#include <hip/hip_runtime.h>
#include <hip/hip_bf16.h>
#include <cstdint>

#define NNODE 256
#define NBT   96
#define LOG2E 1.4426950408889634f

typedef __attribute__((ext_vector_type(8))) short short8;
typedef __attribute__((ext_vector_type(4))) float f32x4;

// round-to-nearest-even pack of two f32 into bf16x2 (lo=a, hi=b)
__device__ __forceinline__ unsigned pack_bf16x2(float a, float b) {
  unsigned ua = __float_as_uint(a);
  unsigned ub = __float_as_uint(b);
  unsigned ra = (ua + 0x7FFFu + ((ua >> 16) & 1u)) >> 16;
  unsigned rb = ((ub + 0x7FFFu + ((ub >> 16) & 1u)) >> 16) << 16;
  return ra | rb;
}
__device__ __forceinline__ unsigned short bf16_rn(float a) {
  unsigned ua = __float_as_uint(a);
  return (unsigned short)((ua + 0x7FFFu + ((ua >> 16) & 1u)) >> 16);
}
__device__ __forceinline__ float blo(unsigned u) { return __uint_as_float(u << 16); }
__device__ __forceinline__ float bhi(unsigned u) { return __uint_as_float(u & 0xFFFF0000u); }

// ---------------------------------------------------------------------------
// Kernel 1: bit-pack adjacency transposed. grid (96, 8), 256 thr.
// mb[bt][j][w] bit b = (adj[bt][32w+b][j] != 0)
// ---------------------------------------------------------------------------
__global__ __launch_bounds__(256) void pack_mask_kernel(const int* __restrict__ adj,
                                                        unsigned* __restrict__ mb) {
  const int bt = blockIdx.x, w = blockIdx.y, j = threadIdx.x;
  const int* a = adj + (size_t)bt * NNODE * NNODE + (size_t)w * 32 * NNODE;
  unsigned v = 0;
#pragma unroll
  for (int b = 0; b < 32; ++b)
    v |= (a[b * NNODE + j] != 0 ? 1u : 0u) << b;
  mb[((size_t)bt * NNODE + j) * 8 + w] = v;
}

// ---------------------------------------------------------------------------
// Kernel 2: small embedding chains (unchanged — verified).
// ---------------------------------------------------------------------------
__global__ __launch_bounds__(64) void embed_kernel(
    const float* __restrict__ te, const float* __restrict__ se, const float* __restrict__ pe,
    const float* __restrict__ Wt, const float* __restrict__ bt_,
    const float* __restrict__ Ws, const float* __restrict__ bs_,
    const float* __restrict__ Wp, const float* __restrict__ bp_,
    const float* __restrict__ Wfc, const float* __restrict__ bfc,
    const float* __restrict__ Wout, const float* __restrict__ bout,
    float* __restrict__ tW, float* __restrict__ spW) {
  const int j = threadIdx.x;
  __shared__ float A[64], Bv[64], C[64], D[64];
  const int blk = blockIdx.x;
  if (blk < NBT) {
    const int row = blk;
    float h = bt_[j];
    for (int k = 0; k < 32; ++k) h += te[row * 32 + k] * Wt[k * 64 + j];
    A[j] = h;
    __syncthreads();
    float tv = bfc[j];
    for (int k = 0; k < 64; ++k) tv += A[k] * Wfc[k * 64 + j];
    Bv[j] = tv;
    __syncthreads();
    float tw = bout[j];
    for (int d = 0; d < 64; ++d) tw += Bv[d] * Wout[(64 + d) * 64 + j];
    tW[row * 64 + j] = tw;
  } else {
    const int n = blk - NBT;
    float sh = bs_[j], ph = bp_[j];
    for (int k = 0; k < 32; ++k) {
      sh += se[n * 32 + k] * Ws[k * 64 + j];
      ph += pe[n * 32 + k] * Wp[k * 64 + j];
    }
    A[j] = sh; Bv[j] = ph;
    __syncthreads();
    float sv = bfc[j], pv = bfc[j];
    for (int k = 0; k < 64; ++k) {
      sv += A[k] * Wfc[k * 64 + j];
      pv += Bv[k] * Wfc[k * 64 + j];
    }
    C[j] = sv; D[j] = pv;
    __syncthreads();
    float spv = bout[j];
    for (int k = 0; k < 64; ++k)
      spv += C[k] * Wout[k * 64 + j] + D[k] * Wout[(64 + k) * 64 + j];
    __syncthreads();
    A[j] = spv;
    __syncthreads();
    float spw = 0.f;
    for (int d = 0; d < 64; ++d) spw += A[d] * Wout[(64 + d) * 64 + j];
    spW[n * 64 + j] = spw;
  }
}

// ---------------------------------------------------------------------------
// Kernel 2b: WoT[c][d] = bf16(Wout[d][c]) for the fused agg2 epilogue MFMA.
// ---------------------------------------------------------------------------
__global__ __launch_bounds__(256) void prep_kernel(const float* __restrict__ Wout,
                                                   unsigned short* __restrict__ WoT) {
  const int tid = threadIdx.x;
  const int c = tid >> 2, d0 = (tid & 3) * 16;
#pragma unroll
  for (int i = 0; i < 16; ++i)
    WoT[c * 64 + d0 + i] = bf16_rn(Wout[(size_t)(d0 + i) * 64 + c]);
}

// ---------------------------------------------------------------------------
// Kernel 3: feat1 — hp = x @ W1[:, head*64:+64]; emits hpT1[bh][d][n] bf16
// (coalesced transpose stores) + es1/ed1 (f32, pre-scaled by log2e).
// grid (4, 96), 256 thr = 1 node each.
// ---------------------------------------------------------------------------
__global__ __launch_bounds__(256) void feat1_kernel(
    const float* __restrict__ x, const float* __restrict__ W1,
    const float* __restrict__ a1s, const float* __restrict__ a1d,
    unsigned short* __restrict__ hpT1, float* __restrict__ es1,
    float* __restrict__ ed1) {
  const int head = blockIdx.x, bt = blockIdx.y, tid = threadIdx.x;
  __shared__ float xt[NNODE][33];
  __shared__ float wt[32][64];

  float acc[64];
#pragma unroll
  for (int j = 0; j < 64; ++j) acc[j] = 0.f;

  const float* xrow = x + ((size_t)bt * NNODE + tid) * 64;
  for (int chunk = 0; chunk < 2; ++chunk) {
    const int k0 = chunk * 32;
#pragma unroll
    for (int qq = 0; qq < 8; ++qq) {
      float4 v = *reinterpret_cast<const float4*>(xrow + k0 + qq * 4);
      xt[tid][qq * 4 + 0] = v.x; xt[tid][qq * 4 + 1] = v.y;
      xt[tid][qq * 4 + 2] = v.z; xt[tid][qq * 4 + 3] = v.w;
    }
#pragma unroll
    for (int i = 0; i < 8; ++i) {
      int l = tid + i * 256, r = l >> 6, c = l & 63;
      wt[r][c] = W1[(size_t)(k0 + r) * 256 + head * 64 + c];
    }
    __syncthreads();
#pragma unroll 4
    for (int kk = 0; kk < 32; ++kk) {
      float xv = xt[tid][kk];
#pragma unroll
      for (int qq = 0; qq < 16; ++qq) {
        float4 wv = *reinterpret_cast<const float4*>(&wt[kk][qq * 4]);
        acc[qq * 4 + 0] += xv * wv.x; acc[qq * 4 + 1] += xv * wv.y;
        acc[qq * 4 + 2] += xv * wv.z; acc[qq * 4 + 3] += xv * wv.w;
      }
    }
    __syncthreads();
  }

  float esv = 0.f, edv = 0.f;
  const float* as = a1s + head * 64;
  const float* ad = a1d + head * 64;
#pragma unroll
  for (int d = 0; d < 64; ++d) { esv += acc[d] * as[d]; edv += acc[d] * ad[d]; }
  const int bh = bt * 4 + head;
  es1[bh * 256 + tid] = esv * LOG2E;
  ed1[bh * 256 + tid] = edv * LOG2E;

  // transpose store: lane n writes column n of hpT1[bh][d][:] — fully coalesced
  unsigned short* go = hpT1 + (size_t)bh * 64 * 256 + tid;
#pragma unroll
  for (int d = 0; d < 64; ++d) go[(size_t)d * 256] = bf16_rn(acc[d]);
}

// ---------------------------------------------------------------------------
// Kernel 4: agg1 — MFMA masked-softmax aggregation, layer 1.
// grid (96, 4), 256 thr = 4 waves; wave w owns j-rows w*64..+63.
// A-frag = P (computed in-register in fragment layout), B = hpT (LDS),
// denominator via ones-B MFMA (row-aligned with C frags).
// ---------------------------------------------------------------------------
__global__ __launch_bounds__(256, 2) void agg1_kernel(
    const unsigned* __restrict__ hpT1, const unsigned* __restrict__ mbg,
    const float* __restrict__ es1, const float* __restrict__ ed1,
    const float* __restrict__ b1, unsigned* __restrict__ hgl) {
  const int bt = blockIdx.x, head = blockIdx.y, tid = threadIdx.x;
  __shared__ union U1 {
    unsigned hpT[64][132];         // 33792 B  (B-operand, padded rows)
    unsigned short ob[256][72];    // 36864 B  (output transpose buffer)
  } sm;
  __shared__ unsigned mbs[NNODE][8];
  __shared__ float ess[NNODE], eds[NNODE];

  const int bh = bt * 4 + head;
  const unsigned* gh = hpT1 + (size_t)bh * 64 * 128;
#pragma unroll
  for (int c = 0; c < 8; ++c) {
    int i4 = tid + c * 256;
    int row = i4 >> 5, col = (i4 & 31) << 2;
    *reinterpret_cast<uint4*>(&sm.hpT[row][col]) =
        *reinterpret_cast<const uint4*>(&gh[row * 128 + col]);
  }
  {
    const unsigned* gm = mbg + ((size_t)bt * NNODE + tid) * 8;
    *reinterpret_cast<uint4*>(&mbs[tid][0]) = reinterpret_cast<const uint4*>(gm)[0];
    *reinterpret_cast<uint4*>(&mbs[tid][4]) = reinterpret_cast<const uint4*>(gm)[1];
  }
  ess[tid] = es1[bh * 256 + tid];
  eds[tid] = ed1[bh * 256 + tid];
  __syncthreads();

  const int lane = tid & 63, wv = tid >> 6;
  const int m = lane & 15, q = lane >> 4;
  const f32x4 z4 = {0.f, 0.f, 0.f, 0.f};
  f32x4 cacc[4][4], cden[4];
#pragma unroll
  for (int jt = 0; jt < 4; ++jt) {
    cden[jt] = z4;
#pragma unroll
    for (int nt = 0; nt < 4; ++nt) cacc[jt][nt] = z4;
  }
  float edv[4];
#pragma unroll
  for (int jt = 0; jt < 4; ++jt) edv[jt] = eds[(wv * 4 + jt) * 16 + m];
  const short8 ones8 = {(short)0x3F80, (short)0x3F80, (short)0x3F80, (short)0x3F80,
                        (short)0x3F80, (short)0x3F80, (short)0x3F80, (short)0x3F80};

  for (int kt = 0; kt < 8; ++kt) {
    short8 bfr[4];
#pragma unroll
    for (int nt = 0; nt < 4; ++nt)
      bfr[nt] = *reinterpret_cast<const short8*>(&sm.hpT[nt * 16 + m][kt * 16 + q * 4]);
    float e[8];
    *reinterpret_cast<float4*>(&e[0]) =
        *reinterpret_cast<const float4*>(&ess[kt * 32 + q * 8]);
    *reinterpret_cast<float4*>(&e[4]) =
        *reinterpret_cast<const float4*>(&ess[kt * 32 + q * 8 + 4]);
#pragma unroll
    for (int jt = 0; jt < 4; ++jt) {
      const unsigned bits = mbs[(wv * 4 + jt) * 16 + m][kt] >> (q * 8);
      float pv[8];
#pragma unroll
      for (int r = 0; r < 8; ++r) {
        float sc = e[r] + edv[jt];
        sc = fmaxf(sc, 0.2f * sc);         // leaky (log2e pre-folded upstream)
        pv[r] = ((bits >> r) & 1u) ? exp2f(sc) : 0.f;
      }
      union { unsigned u[4]; short8 s; } A;
#pragma unroll
      for (int h = 0; h < 4; ++h) A.u[h] = pack_bf16x2(pv[2 * h], pv[2 * h + 1]);
#pragma unroll
      for (int nt = 0; nt < 4; ++nt)
        cacc[jt][nt] = __builtin_amdgcn_mfma_f32_16x16x32_bf16(A.s, bfr[nt],
                                                               cacc[jt][nt], 0, 0, 0);
      cden[jt] = __builtin_amdgcn_mfma_f32_16x16x32_bf16(A.s, ones8, cden[jt], 0, 0, 0);
    }
  }
  __syncthreads();   // all hpT reads done before ob overlay writes

  float b1v[4];
#pragma unroll
  for (int nt = 0; nt < 4; ++nt) b1v[nt] = b1[head * 64 + nt * 16 + m];
#pragma unroll
  for (int jt = 0; jt < 4; ++jt) {
#pragma unroll
    for (int reg = 0; reg < 4; ++reg) {
      const int j = (wv * 4 + jt) * 16 + q * 4 + reg;
      const float inv = 1.f / fmaxf(cden[jt][reg], 1e-30f);
#pragma unroll
      for (int nt = 0; nt < 4; ++nt) {
        float v = cacc[jt][nt][reg] * inv + b1v[nt];
        v = v > 0.f ? v : expm1f(v);
        sm.ob[j][nt * 16 + m] = bf16_rn(v);
      }
    }
  }
  __syncthreads();
  // FIX (round 4 bug): full 256 rows x 32 uints via 2048 uint4 stores
  // (previous loop only covered rows 0..63 — 3/4 of h was left as poison).
  unsigned* go = hgl + (size_t)bt * NNODE * 128 + head * 32;
#pragma unroll
  for (int c = 0; c < 8; ++c) {
    int i4 = tid + c * 256;
    int j = i4 >> 3, col = (i4 & 7) * 4;
    *reinterpret_cast<uint4*>(&go[(size_t)j * 128 + col]) =
        *reinterpret_cast<const uint4*>(&sm.ob[j][col * 2]);
  }
}

// ---------------------------------------------------------------------------
// Kernel 5: feat2 — hp2 = h @ W2 (K=256); emits hpT2[bt][c][n] bf16 + es2/ed2.
// grid (96, 4), 256 thr; wave p owns output-dim quarter p*16..+16, lane = node.
// ---------------------------------------------------------------------------
__global__ __launch_bounds__(256, 2) void feat2_kernel(
    const unsigned* __restrict__ hgl, const float* __restrict__ W2,
    const float* __restrict__ a2s, const float* __restrict__ a2d,
    unsigned short* __restrict__ hpT2, float* __restrict__ es2,
    float* __restrict__ ed2) {
  const int bt = blockIdx.x, g = blockIdx.y, tid = threadIdx.x;
  const int p = tid >> 6, nl = tid & 63;
  __shared__ unsigned ht[64][130];
  __shared__ unsigned w2l[256][33];
  __shared__ float esp[64][4], edp[64][4];

  const unsigned* hrow = hgl + ((size_t)bt * NNODE + g * 64 + nl) * 128 + p * 32;
#pragma unroll
  for (int qq = 0; qq < 8; ++qq)
    *reinterpret_cast<uint4*>(&ht[nl][p * 32 + qq * 4]) =
        reinterpret_cast<const uint4*>(hrow)[qq];
  {
    const float* wr = W2 + (size_t)tid * 64;
#pragma unroll
    for (int qq = 0; qq < 8; ++qq) {
      float4 w0 = reinterpret_cast<const float4*>(wr)[2 * qq];
      float4 w1 = reinterpret_cast<const float4*>(wr)[2 * qq + 1];
      uint4 u;
      u.x = pack_bf16x2(w0.x, w0.y); u.y = pack_bf16x2(w0.z, w0.w);
      u.z = pack_bf16x2(w1.x, w1.y); u.w = pack_bf16x2(w1.z, w1.w);
      *reinterpret_cast<uint4*>(&w2l[tid][qq * 4]) = u;
    }
  }
  __syncthreads();

  float acc[16];
#pragma unroll
  for (int i = 0; i < 16; ++i) acc[i] = 0.f;

  for (int kp = 0; kp < 128; ++kp) {
    const unsigned hu = ht[nl][kp];
    const float h0 = blo(hu), h1 = bhi(hu);
    const int k0 = 2 * kp, k1 = 2 * kp + 1;
#pragma unroll
    for (int qq = 0; qq < 2; ++qq) {
      uint4 u0 = *reinterpret_cast<const uint4*>(&w2l[k0][p * 8 + qq * 4]);
      uint4 u1 = *reinterpret_cast<const uint4*>(&w2l[k1][p * 8 + qq * 4]);
      acc[qq * 8 + 0] += h0 * blo(u0.x) + h1 * blo(u1.x);
      acc[qq * 8 + 1] += h0 * bhi(u0.x) + h1 * bhi(u1.x);
      acc[qq * 8 + 2] += h0 * blo(u0.y) + h1 * blo(u1.y);
      acc[qq * 8 + 3] += h0 * bhi(u0.y) + h1 * bhi(u1.y);
      acc[qq * 8 + 4] += h0 * blo(u0.z) + h1 * blo(u1.z);
      acc[qq * 8 + 5] += h0 * bhi(u0.z) + h1 * bhi(u1.z);
      acc[qq * 8 + 6] += h0 * blo(u0.w) + h1 * blo(u1.w);
      acc[qq * 8 + 7] += h0 * bhi(u0.w) + h1 * bhi(u1.w);
    }
  }

  // transpose store: lane nl writes column (g*64+nl) of hpT2 rows c — coalesced
  unsigned short* gbase = hpT2 + (size_t)bt * 64 * 256 + (size_t)g * 64 + nl;
#pragma unroll
  for (int i = 0; i < 16; ++i)
    gbase[(size_t)(p * 16 + i) * 256] = bf16_rn(acc[i]);

  float esv = 0.f, edv = 0.f;
#pragma unroll
  for (int i = 0; i < 16; ++i) {
    esv += acc[i] * a2s[p * 16 + i];
    edv += acc[i] * a2d[p * 16 + i];
  }
  esp[nl][p] = esv; edp[nl][p] = edv;
  __syncthreads();
  if (tid < 64) {
    float e = (esp[tid][0] + esp[tid][1] + esp[tid][2] + esp[tid][3]) * LOG2E;
    float d = (edp[tid][0] + edp[tid][1] + edp[tid][2] + edp[tid][3]) * LOG2E;
    es2[bt * NNODE + g * 64 + tid] = e;
    ed2[bt * NNODE + g * 64 + tid] = d;
  }
}

// ---------------------------------------------------------------------------
// Kernel 6: agg2 — MFMA aggregation (1 head) + fused od@Wout + spW + tW.
// grid (96), 256 thr = 4 waves.
// ---------------------------------------------------------------------------
__global__ __launch_bounds__(256, 2) void agg2_kernel(
    const unsigned* __restrict__ hpT2u, const unsigned* __restrict__ mbg,
    const float* __restrict__ es2, const float* __restrict__ ed2,
    const float* __restrict__ b2, const unsigned* __restrict__ WoTg,
    const float* __restrict__ spW, const float* __restrict__ tW,
    float* __restrict__ out) {
  const int bt = blockIdx.x, tid = threadIdx.x;
  __shared__ union U2 {
    unsigned hpT[64][132];
    unsigned short ob[256][72];    // od buffer (phase-2 A operand)
  } sm;
  __shared__ unsigned wol[64][36];
  __shared__ unsigned mbs[NNODE][8];
  __shared__ float ess[NNODE], eds[NNODE];

  const unsigned* gh = hpT2u + (size_t)bt * 64 * 128;
#pragma unroll
  for (int c = 0; c < 8; ++c) {
    int i4 = tid + c * 256;
    int row = i4 >> 5, col = (i4 & 31) << 2;
    *reinterpret_cast<uint4*>(&sm.hpT[row][col]) =
        *reinterpret_cast<const uint4*>(&gh[row * 128 + col]);
  }
#pragma unroll
  for (int c = 0; c < 8; ++c) {
    int iu = tid + c * 256;
    wol[iu >> 5][iu & 31] = WoTg[(iu >> 5) * 32 + (iu & 31)];
  }
  {
    const unsigned* gm = mbg + ((size_t)bt * NNODE + tid) * 8;
    *reinterpret_cast<uint4*>(&mbs[tid][0]) = reinterpret_cast<const uint4*>(gm)[0];
    *reinterpret_cast<uint4*>(&mbs[tid][4]) = reinterpret_cast<const uint4*>(gm)[1];
  }
  ess[tid] = es2[bt * NNODE + tid];
  eds[tid] = ed2[bt * NNODE + tid];
  __syncthreads();

  const int lane = tid & 63, wv = tid >> 6;
  const int m = lane & 15, q = lane >> 4;
  const f32x4 z4 = {0.f, 0.f, 0.f, 0.f};
  f32x4 cacc[4][4], cden[4];
#pragma unroll
  for (int jt = 0; jt < 4; ++jt) {
    cden[jt] = z4;
#pragma unroll
    for (int nt = 0; nt < 4; ++nt) cacc[jt][nt] = z4;
  }
  float edv[4];
#pragma unroll
  for (int jt = 0; jt < 4; ++jt) edv[jt] = eds[(wv * 4 + jt) * 16 + m];
  const short8 ones8 = {(short)0x3F80, (short)0x3F80, (short)0x3F80, (short)0x3F80,
                        (short)0x3F80, (short)0x3F80, (short)0x3F80, (short)0x3F80};

  for (int kt = 0; kt < 8; ++kt) {
    short8 bfr[4];
#pragma unroll
    for (int nt = 0; nt < 4; ++nt)
      bfr[nt] = *reinterpret_cast<const short8*>(&sm.hpT[nt * 16 + m][kt * 16 + q * 4]);
    float e[8];
    *reinterpret_cast<float4*>(&e[0]) =
        *reinterpret_cast<const float4*>(&ess[kt * 32 + q * 8]);
    *reinterpret_cast<float4*>(&e[4]) =
        *reinterpret_cast<const float4*>(&ess[kt * 32 + q * 8 + 4]);
#pragma unroll
    for (int jt = 0; jt < 4; ++jt) {
      const unsigned bits = mbs[(wv * 4 + jt) * 16 + m][kt] >> (q * 8);
      float pv[8];
#pragma unroll
      for (int r = 0; r < 8; ++r) {
        float sc = e[r] + edv[jt];
        sc = fmaxf(sc, 0.2f * sc);
        pv[r] = ((bits >> r) & 1u) ? exp2f(sc) : 0.f;
      }
      union { unsigned u[4]; short8 s; } A;
#pragma unroll
      for (int h = 0; h < 4; ++h) A.u[h] = pack_bf16x2(pv[2 * h], pv[2 * h + 1]);
#pragma unroll
      for (int nt = 0; nt < 4; ++nt)
        cacc[jt][nt] = __builtin_amdgcn_mfma_f32_16x16x32_bf16(A.s, bfr[nt],
                                                               cacc[jt][nt], 0, 0, 0);
      cden[jt] = __builtin_amdgcn_mfma_f32_16x16x32_bf16(A.s, ones8, cden[jt], 0, 0, 0);
    }
  }
  __syncthreads();   // hpT reads done before ob overlay writes

  float b2v[4];
#pragma unroll
  for (int nt = 0; nt < 4; ++nt) b2v[nt] = b2[nt * 16 + m];
#pragma unroll
  for (int jt = 0; jt < 4; ++jt) {
#pragma unroll
    for (int reg = 0; reg < 4; ++reg) {
      const int j = (wv * 4 + jt) * 16 + q * 4 + reg;
      const float inv = 1.f / fmaxf(cden[jt][reg], 1e-30f);
#pragma unroll
      for (int nt = 0; nt < 4; ++nt)
        sm.ob[j][nt * 16 + m] = bf16_rn(cacc[jt][nt][reg] * inv + b2v[nt]);
    }
  }
  __syncthreads();

  // phase 2: out = od @ Wout[0:64] (+ spW + tW)
  f32x4 c2[4][4];
#pragma unroll
  for (int jt = 0; jt < 4; ++jt)
#pragma unroll
    for (int ct = 0; ct < 4; ++ct) c2[jt][ct] = z4;
#pragma unroll
  for (int kt2 = 0; kt2 < 2; ++kt2) {
    short8 bw[4];
#pragma unroll
    for (int ct = 0; ct < 4; ++ct)
      bw[ct] = *reinterpret_cast<const short8*>(&wol[ct * 16 + m][kt2 * 16 + q * 4]);
    short8 a2f[4];
#pragma unroll
    for (int jt = 0; jt < 4; ++jt)
      a2f[jt] = *reinterpret_cast<const short8*>(
          &sm.ob[(wv * 4 + jt) * 16 + m][kt2 * 32 + q * 8]);
#pragma unroll
    for (int jt = 0; jt < 4; ++jt)
#pragma unroll
      for (int ct = 0; ct < 4; ++ct)
        c2[jt][ct] = __builtin_amdgcn_mfma_f32_16x16x32_bf16(a2f[jt], bw[ct],
                                                             c2[jt][ct], 0, 0, 0);
  }
  float tWv[4];
#pragma unroll
  for (int ct = 0; ct < 4; ++ct) tWv[ct] = tW[bt * 64 + ct * 16 + m];
#pragma unroll
  for (int jt = 0; jt < 4; ++jt) {
#pragma unroll
    for (int reg = 0; reg < 4; ++reg) {
      const int j = (wv * 4 + jt) * 16 + q * 4 + reg;
#pragma unroll
      for (int ct = 0; ct < 4; ++ct) {
        const int cc = ct * 16 + m;
        out[((size_t)bt * NNODE + j) * 64 + cc] =
            c2[jt][ct][reg] + spW[j * 64 + cc] + tWv[ct];
      }
    }
  }
}

// ---------------------------------------------------------------------------
extern "C" void kernel_launch(void* const* d_in, const int* in_sizes, int n_in,
                              void* d_out, int out_size, void* d_ws, size_t ws_size,
                              hipStream_t stream) {
  const float* x    = (const float*)d_in[0];
  const int*   adj  = (const int*)d_in[1];
  const float* te   = (const float*)d_in[2];
  const float* se   = (const float*)d_in[3];
  const float* pe   = (const float*)d_in[4];
  const float* Wt   = (const float*)d_in[5];
  const float* bt_  = (const float*)d_in[6];
  const float* Ws   = (const float*)d_in[7];
  const float* bs_  = (const float*)d_in[8];
  const float* Wp   = (const float*)d_in[9];
  const float* bp_  = (const float*)d_in[10];
  const float* Wfc  = (const float*)d_in[11];
  const float* bfc  = (const float*)d_in[12];
  const float* Wout = (const float*)d_in[13];
  const float* bout = (const float*)d_in[14];
  const float* W1   = (const float*)d_in[15];
  const float* b1   = (const float*)d_in[16];
  const float* a1s  = (const float*)d_in[17];
  const float* a1d  = (const float*)d_in[18];
  const float* W2   = (const float*)d_in[19];
  const float* b2   = (const float*)d_in[20];
  const float* a2s  = (const float*)d_in[21];
  const float* a2d  = (const float*)d_in[22];

  // workspace layout (26,836,992 B)
  char* ws = (char*)d_ws;
  unsigned*       mb   = (unsigned*)(ws);                 // 786432
  float*          tW   = (float*)(ws + 786432);           // 24576
  float*          spW  = (float*)(ws + 811008);           // 65536
  unsigned short* WoT  = (unsigned short*)(ws + 876544);  // 8192
  float*          es12 = (float*)(ws + 884736);           // 393216 (es1, later es2)
  float*          ed12 = (float*)(ws + 1277952);          // 393216 (ed1, later ed2)
  unsigned short* hpT  = (unsigned short*)(ws + 1671168); // 12582912 (hpT1, later hpT2)
  unsigned*       hgl  = (unsigned*)(ws + 14254080);      // 12582912

  pack_mask_kernel<<<dim3(NBT, 8), 256, 0, stream>>>(adj, mb);
  embed_kernel<<<NBT + NNODE, 64, 0, stream>>>(te, se, pe, Wt, bt_, Ws, bs_,
                                               Wp, bp_, Wfc, bfc, Wout, bout, tW, spW);
  prep_kernel<<<1, 256, 0, stream>>>(Wout, WoT);
  feat1_kernel<<<dim3(4, NBT), 256, 0, stream>>>(x, W1, a1s, a1d, hpT, es12, ed12);
  agg1_kernel<<<dim3(NBT, 4), 256, 0, stream>>>((const unsigned*)hpT, mb, es12, ed12,
                                                b1, hgl);
  feat2_kernel<<<dim3(NBT, 4), 256, 0, stream>>>(hgl, W2, a2s, a2d, hpT, es12, ed12);
  agg2_kernel<<<NBT, 256, 0, stream>>>((const unsigned*)hpT, mb, es12, ed12, b2,
                                       (const unsigned*)WoT, spW, tW, (float*)d_out);
}

// Round 7
// 183.027 us; speedup vs baseline: 3.7643x; 1.3673x over previous
//
#include <hip/hip_runtime.h>
#include <hip/hip_bf16.h>
#include <cstdint>

#define NNODE 256
#define NBT   96
#define LOG2E 1.4426950408889634f

typedef __attribute__((ext_vector_type(8))) short short8;
typedef __attribute__((ext_vector_type(4))) float f32x4;

__device__ __forceinline__ unsigned pack_bf16x2(float a, float b) {
  unsigned ua = __float_as_uint(a);
  unsigned ub = __float_as_uint(b);
  unsigned ra = (ua + 0x7FFFu + ((ua >> 16) & 1u)) >> 16;
  unsigned rb = ((ub + 0x7FFFu + ((ub >> 16) & 1u)) >> 16) << 16;
  return ra | rb;
}
__device__ __forceinline__ unsigned short bf16_rn(float a) {
  unsigned ua = __float_as_uint(a);
  return (unsigned short)((ua + 0x7FFFu + ((ua >> 16) & 1u)) >> 16);
}
__device__ __forceinline__ float blo(unsigned u) { return __uint_as_float(u << 16); }
__device__ __forceinline__ float bhi(unsigned u) { return __uint_as_float(u & 0xFFFF0000u); }

// ---------------------------------------------------------------------------
// Kernel 1: bit-pack adjacency, layout [bt][w][j] (w = source 32-chunk).
// bit b of mb[bt][w][j] = (adj[bt][32w+b][j] != 0)
// ---------------------------------------------------------------------------
__global__ __launch_bounds__(256) void pack_mask_kernel(const int* __restrict__ adj,
                                                        unsigned* __restrict__ mb) {
  const int bt = blockIdx.x, w = blockIdx.y, j = threadIdx.x;
  const int* a = adj + (size_t)bt * NNODE * NNODE + (size_t)w * 32 * NNODE;
  unsigned v = 0;
#pragma unroll
  for (int b = 0; b < 32; ++b)
    v |= (a[b * NNODE + j] != 0 ? 1u : 0u) << b;
  mb[((size_t)bt * 8 + w) * 256 + j] = v;
}

// ---------------------------------------------------------------------------
// Kernel 2: small embedding chains (unchanged — verified).
// ---------------------------------------------------------------------------
__global__ __launch_bounds__(64) void embed_kernel(
    const float* __restrict__ te, const float* __restrict__ se, const float* __restrict__ pe,
    const float* __restrict__ Wt, const float* __restrict__ bt_,
    const float* __restrict__ Ws, const float* __restrict__ bs_,
    const float* __restrict__ Wp, const float* __restrict__ bp_,
    const float* __restrict__ Wfc, const float* __restrict__ bfc,
    const float* __restrict__ Wout, const float* __restrict__ bout,
    float* __restrict__ tW, float* __restrict__ spW) {
  const int j = threadIdx.x;
  __shared__ float A[64], Bv[64], C[64], D[64];
  const int blk = blockIdx.x;
  if (blk < NBT) {
    const int row = blk;
    float h = bt_[j];
    for (int k = 0; k < 32; ++k) h += te[row * 32 + k] * Wt[k * 64 + j];
    A[j] = h;
    __syncthreads();
    float tv = bfc[j];
    for (int k = 0; k < 64; ++k) tv += A[k] * Wfc[k * 64 + j];
    Bv[j] = tv;
    __syncthreads();
    float tw = bout[j];
    for (int d = 0; d < 64; ++d) tw += Bv[d] * Wout[(64 + d) * 64 + j];
    tW[row * 64 + j] = tw;
  } else {
    const int n = blk - NBT;
    float sh = bs_[j], ph = bp_[j];
    for (int k = 0; k < 32; ++k) {
      sh += se[n * 32 + k] * Ws[k * 64 + j];
      ph += pe[n * 32 + k] * Wp[k * 64 + j];
    }
    A[j] = sh; Bv[j] = ph;
    __syncthreads();
    float sv = bfc[j], pv = bfc[j];
    for (int k = 0; k < 64; ++k) {
      sv += A[k] * Wfc[k * 64 + j];
      pv += Bv[k] * Wfc[k * 64 + j];
    }
    C[j] = sv; D[j] = pv;
    __syncthreads();
    float spv = bout[j];
    for (int k = 0; k < 64; ++k)
      spv += C[k] * Wout[k * 64 + j] + D[k] * Wout[(64 + k) * 64 + j];
    __syncthreads();
    A[j] = spv;
    __syncthreads();
    float spw = 0.f;
    for (int d = 0; d < 64; ++d) spw += A[d] * Wout[(64 + d) * 64 + j];
    spW[n * 64 + j] = spw;
  }
}

// ---------------------------------------------------------------------------
// Kernel 2b: prep transposed bf16 weights.
//  block 0: WoT[c][d]=Wout[d][c] (64x64) ; W2T[d][k]=W2[k][d] (64x256)
//  block 1: W1T[hd][k]=W1[k][hd] (256x64)
// ---------------------------------------------------------------------------
__global__ __launch_bounds__(256) void prep_kernel(
    const float* __restrict__ Wout, const float* __restrict__ W1,
    const float* __restrict__ W2, unsigned short* __restrict__ WoT,
    unsigned short* __restrict__ W1T, unsigned short* __restrict__ W2T) {
  const int tid = threadIdx.x;
  if (blockIdx.x == 0) {
    {
      const int c = tid >> 2, d0 = (tid & 3) * 16;
#pragma unroll
      for (int i = 0; i < 16; ++i)
        WoT[c * 64 + d0 + i] = bf16_rn(Wout[(size_t)(d0 + i) * 64 + c]);
    }
    // W2T: thread = k row of W2
    const int k = tid;
#pragma unroll
    for (int d = 0; d < 64; ++d)
      W2T[d * 256 + k] = bf16_rn(W2[(size_t)k * 64 + d]);
  } else {
    // FIX (round 6 bug): clean 32-uint transpose per hd row.
    // Previous version skipped half the k-rows (++p inside loop) and read
    // u[16..31] out of bounds of u[16] — W1T was half garbage.
    const int hd = tid;
    unsigned u[32];
#pragma unroll
    for (int p = 0; p < 32; ++p) {
      float a = W1[(size_t)(2 * p) * 256 + hd];
      float b = W1[(size_t)(2 * p + 1) * 256 + hd];
      u[p] = pack_bf16x2(a, b);
    }
    unsigned* o = (unsigned*)(W1T + (size_t)hd * 64);
#pragma unroll
    for (int p = 0; p < 8; ++p) {
      uint4 v;
      v.x = u[4 * p + 0]; v.y = u[4 * p + 1];
      v.z = u[4 * p + 2]; v.w = u[4 * p + 3];
      *reinterpret_cast<uint4*>(o + 4 * p) = v;
    }
  }
}

// ---------------------------------------------------------------------------
// Kernel 3: feat1 (MFMA) — hpT1[bh][d][n] = (x @ W1[:,head*64+d]) as bf16.
// grid (4, 96), 256 thr / 4 waves. A = W1T slice [d][k], B = x [n][k] (bf16 LDS).
// ---------------------------------------------------------------------------
__global__ __launch_bounds__(256) void feat1_kernel(
    const float* __restrict__ x, const unsigned* __restrict__ W1Tu,
    unsigned short* __restrict__ hpT1) {
  const int head = blockIdx.x, bt = blockIdx.y, tid = threadIdx.x;
  __shared__ unsigned xb[256][36];   // 256 nodes x 64 bf16 (+pad)
  __shared__ unsigned w1t[64][36];   // 64 d x 64 bf16 (+pad)

  {
    const float* xrow = x + ((size_t)bt * NNODE + tid) * 64;
    unsigned u[32];
#pragma unroll
    for (int p = 0; p < 16; ++p) {
      float4 v = reinterpret_cast<const float4*>(xrow)[p];
      u[2 * p] = pack_bf16x2(v.x, v.y);
      u[2 * p + 1] = pack_bf16x2(v.z, v.w);
    }
#pragma unroll
    for (int p = 0; p < 8; ++p) {
      uint4 v; v.x = u[4 * p]; v.y = u[4 * p + 1]; v.z = u[4 * p + 2]; v.w = u[4 * p + 3];
      *reinterpret_cast<uint4*>(&xb[tid][4 * p]) = v;
    }
  }
  {
    const int r = tid >> 2, c0 = (tid & 3) * 8;
    const unsigned* src = W1Tu + ((size_t)(head * 64 + r) * 32) + c0;
    *reinterpret_cast<uint4*>(&w1t[r][c0]) = *reinterpret_cast<const uint4*>(src);
    *reinterpret_cast<uint4*>(&w1t[r][c0 + 4]) = *reinterpret_cast<const uint4*>(src + 4);
  }
  __syncthreads();

  const int lane = tid & 63, wv = tid >> 6;
  const int m = lane & 15, q = lane >> 4;
  const f32x4 z4 = {0.f, 0.f, 0.f, 0.f};
  f32x4 cf[4][4];
#pragma unroll
  for (int mt = 0; mt < 4; ++mt)
#pragma unroll
    for (int nt = 0; nt < 4; ++nt) cf[mt][nt] = z4;

#pragma unroll
  for (int kt = 0; kt < 2; ++kt) {
    short8 af[4], bf[4];
#pragma unroll
    for (int mt = 0; mt < 4; ++mt)
      af[mt] = *reinterpret_cast<const short8*>(&w1t[mt * 16 + m][kt * 16 + q * 4]);
#pragma unroll
    for (int nt = 0; nt < 4; ++nt)
      bf[nt] = *reinterpret_cast<const short8*>(&xb[wv * 64 + nt * 16 + m][kt * 16 + q * 4]);
#pragma unroll
    for (int mt = 0; mt < 4; ++mt)
#pragma unroll
      for (int nt = 0; nt < 4; ++nt)
        cf[mt][nt] = __builtin_amdgcn_mfma_f32_16x16x32_bf16(af[mt], bf[nt], cf[mt][nt], 0, 0, 0);
  }

  unsigned short* go = hpT1 + (size_t)(bt * 4 + head) * 16384;
#pragma unroll
  for (int mt = 0; mt < 4; ++mt)
#pragma unroll
    for (int nt = 0; nt < 4; ++nt)
#pragma unroll
      for (int reg = 0; reg < 4; ++reg) {
        const int d = mt * 16 + q * 4 + reg;
        const int n = wv * 64 + nt * 16 + m;
        go[d * 256 + n] = bf16_rn(cf[mt][nt][reg]);
      }
}

// ---------------------------------------------------------------------------
// Kernel 4: agg1 — MFMA masked-softmax aggregation, layer 1.
// grid (96,4), 512 thr / 8 waves; wave owns 32 j-rows (2 jt).
// es/ed computed in-block from staged bf16 hpT.
// ---------------------------------------------------------------------------
__global__ __launch_bounds__(512, 2) void agg1_kernel(
    const unsigned* __restrict__ hpT1u, const unsigned* __restrict__ mbg,
    const float* __restrict__ a1s, const float* __restrict__ a1d,
    const float* __restrict__ b1, unsigned* __restrict__ hgl) {
  const int bt = blockIdx.x, head = blockIdx.y, tid = threadIdx.x;
  __shared__ union U1 {
    unsigned hpT[64][132];
    unsigned short ob[256][72];
  } sm;
  __shared__ unsigned mbs[8 * 256];
  __shared__ float ess[256], eds[256];
  __shared__ float asv[64], adv[64];

  const int bh = bt * 4 + head;
  const unsigned* gh = hpT1u + (size_t)bh * 8192;
#pragma unroll
  for (int c = 0; c < 4; ++c) {
    int i4 = tid + c * 512;
    int row = i4 >> 5, col = (i4 & 31) << 2;
    *reinterpret_cast<uint4*>(&sm.hpT[row][col]) =
        *reinterpret_cast<const uint4*>(&gh[row * 128 + col]);
  }
  *reinterpret_cast<uint4*>(&mbs[tid * 4]) =
      *reinterpret_cast<const uint4*>(&mbg[(size_t)bt * 2048 + tid * 4]);
  if (tid < 64) asv[tid] = a1s[head * 64 + tid];
  else if (tid < 128) adv[tid - 64] = a1d[head * 64 + (tid - 64)];
  __syncthreads();

  // es/ed from bf16 hpT columns (conflict-free: pairs broadcast)
  {
    const int n = tid & 255;
    const unsigned sh = (n & 1) * 16;
    const float* av = (tid < 256) ? asv : adv;
    float s = 0.f;
#pragma unroll 8
    for (int d = 0; d < 64; ++d) {
      unsigned u = sm.hpT[d][n >> 1];
      s += __uint_as_float((u >> sh) << 16) * av[d];
    }
    if (tid < 256) ess[n] = s * LOG2E;
    else eds[n] = s * LOG2E;
  }
  __syncthreads();

  const int lane = tid & 63, wv = tid >> 6;
  const int m = lane & 15, q = lane >> 4;
  const f32x4 z4 = {0.f, 0.f, 0.f, 0.f};
  f32x4 cacc[2][4], cden[2];
#pragma unroll
  for (int jt = 0; jt < 2; ++jt) {
    cden[jt] = z4;
#pragma unroll
    for (int nt = 0; nt < 4; ++nt) cacc[jt][nt] = z4;
  }
  float edv[2];
#pragma unroll
  for (int jt = 0; jt < 2; ++jt) edv[jt] = eds[(wv * 2 + jt) * 16 + m];
  const short8 ones8 = {(short)0x3F80, (short)0x3F80, (short)0x3F80, (short)0x3F80,
                        (short)0x3F80, (short)0x3F80, (short)0x3F80, (short)0x3F80};

  for (int kt = 0; kt < 8; ++kt) {
    short8 bfr[4];
#pragma unroll
    for (int nt = 0; nt < 4; ++nt)
      bfr[nt] = *reinterpret_cast<const short8*>(&sm.hpT[nt * 16 + m][kt * 16 + q * 4]);
    float e[8];
    *reinterpret_cast<float4*>(&e[0]) = *reinterpret_cast<const float4*>(&ess[kt * 32 + q * 8]);
    *reinterpret_cast<float4*>(&e[4]) = *reinterpret_cast<const float4*>(&ess[kt * 32 + q * 8 + 4]);
#pragma unroll
    for (int jt = 0; jt < 2; ++jt) {
      const int jr = (wv * 2 + jt) * 16 + m;
      const unsigned bits = mbs[kt * 256 + jr] >> (q * 8);
      float pv[8];
#pragma unroll
      for (int r = 0; r < 8; ++r) {
        float sc = e[r] + edv[jt];
        sc = fmaxf(sc, 0.2f * sc);
        pv[r] = ((bits >> r) & 1u) ? exp2f(sc) : 0.f;
      }
      union { unsigned u[4]; short8 s; } A;
#pragma unroll
      for (int h = 0; h < 4; ++h) A.u[h] = pack_bf16x2(pv[2 * h], pv[2 * h + 1]);
#pragma unroll
      for (int nt = 0; nt < 4; ++nt)
        cacc[jt][nt] = __builtin_amdgcn_mfma_f32_16x16x32_bf16(A.s, bfr[nt], cacc[jt][nt], 0, 0, 0);
      cden[jt] = __builtin_amdgcn_mfma_f32_16x16x32_bf16(A.s, ones8, cden[jt], 0, 0, 0);
    }
  }
  __syncthreads();

  float b1v[4];
#pragma unroll
  for (int nt = 0; nt < 4; ++nt) b1v[nt] = b1[head * 64 + nt * 16 + m];
#pragma unroll
  for (int jt = 0; jt < 2; ++jt) {
#pragma unroll
    for (int reg = 0; reg < 4; ++reg) {
      const int j = (wv * 2 + jt) * 16 + q * 4 + reg;
      const float inv = 1.f / fmaxf(cden[jt][reg], 1e-30f);
#pragma unroll
      for (int nt = 0; nt < 4; ++nt) {
        float v = cacc[jt][nt][reg] * inv + b1v[nt];
        v = v > 0.f ? v : expm1f(v);
        sm.ob[j][nt * 16 + m] = bf16_rn(v);
      }
    }
  }
  __syncthreads();
  unsigned* go = hgl + (size_t)bt * NNODE * 128 + head * 32;
#pragma unroll
  for (int c = 0; c < 4; ++c) {
    int i4 = tid + c * 512;
    int j = i4 >> 3, col = (i4 & 7) * 4;
    *reinterpret_cast<uint4*>(&go[(size_t)j * 128 + col]) =
        *reinterpret_cast<const uint4*>(&sm.ob[j][col * 2]);
  }
}

// ---------------------------------------------------------------------------
// Kernel 5: feat2 (MFMA) — hpT2[bt][d][n] = (h @ W2)[n][d], K=256.
// grid (96, 4 node-groups), 256 thr / 4 waves (wave = 16-node tile).
// ---------------------------------------------------------------------------
__global__ __launch_bounds__(256, 2) void feat2_kernel(
    const unsigned* __restrict__ hglu, const unsigned* __restrict__ W2Tu,
    unsigned short* __restrict__ hpT2) {
  const int bt = blockIdx.x, ng = blockIdx.y, tid = threadIdx.x;
  __shared__ unsigned hb[64][132];
  __shared__ unsigned w2t[64][132];

#pragma unroll
  for (int c = 0; c < 8; ++c) {
    int i4 = tid + c * 256;
    int row = i4 >> 5, col = (i4 & 31) << 2;
    *reinterpret_cast<uint4*>(&hb[row][col]) =
        *reinterpret_cast<const uint4*>(&hglu[((size_t)bt * 256 + ng * 64 + row) * 128 + col]);
    *reinterpret_cast<uint4*>(&w2t[row][col]) =
        *reinterpret_cast<const uint4*>(&W2Tu[row * 128 + col]);
  }
  __syncthreads();

  const int lane = tid & 63, wv = tid >> 6;
  const int m = lane & 15, q = lane >> 4;
  const f32x4 z4 = {0.f, 0.f, 0.f, 0.f};
  f32x4 cf[4];
#pragma unroll
  for (int mt = 0; mt < 4; ++mt) cf[mt] = z4;

  for (int kt = 0; kt < 8; ++kt) {
    short8 bf = *reinterpret_cast<const short8*>(&hb[wv * 16 + m][kt * 16 + q * 4]);
#pragma unroll
    for (int mt = 0; mt < 4; ++mt) {
      short8 af = *reinterpret_cast<const short8*>(&w2t[mt * 16 + m][kt * 16 + q * 4]);
      cf[mt] = __builtin_amdgcn_mfma_f32_16x16x32_bf16(af, bf, cf[mt], 0, 0, 0);
    }
  }

  unsigned short* go = hpT2 + (size_t)bt * 16384;
#pragma unroll
  for (int mt = 0; mt < 4; ++mt)
#pragma unroll
    for (int reg = 0; reg < 4; ++reg) {
      const int d = mt * 16 + q * 4 + reg;
      const int n = ng * 64 + wv * 16 + m;
      go[d * 256 + n] = bf16_rn(cf[mt][reg]);
    }
}

// ---------------------------------------------------------------------------
// Kernel 6: agg2 — MFMA aggregation (1 head) + fused od@Wout + spW + tW.
// grid (96, 2 j-halves), 512 thr / 8 waves (wave = 16 j-rows).
// ---------------------------------------------------------------------------
__global__ __launch_bounds__(512, 2) void agg2_kernel(
    const unsigned* __restrict__ hpT2u, const unsigned* __restrict__ mbg,
    const float* __restrict__ a2s, const float* __restrict__ a2d,
    const float* __restrict__ b2, const unsigned* __restrict__ WoTu,
    const float* __restrict__ spW, const float* __restrict__ tW,
    float* __restrict__ out) {
  const int bt = blockIdx.x, jh = blockIdx.y, tid = threadIdx.x;
  const int jbase = jh * 128;
  __shared__ union U2 {
    unsigned hpT[64][132];
    unsigned short ob[128][72];
  } sm;
  __shared__ unsigned wol[64][36];
  __shared__ unsigned mbs[8 * 128];
  __shared__ float ess[256], eds[128];
  __shared__ float a2sv[64], a2dv[64];

  const unsigned* gh = hpT2u + (size_t)bt * 8192;
#pragma unroll
  for (int c = 0; c < 4; ++c) {
    int i4 = tid + c * 512;
    int row = i4 >> 5, col = (i4 & 31) << 2;
    *reinterpret_cast<uint4*>(&sm.hpT[row][col]) =
        *reinterpret_cast<const uint4*>(&gh[row * 128 + col]);
  }
  {
    int row = tid >> 3, col = (tid & 7) * 4;
    *reinterpret_cast<uint4*>(&wol[row][col]) =
        *reinterpret_cast<const uint4*>(&WoTu[row * 32 + col]);
  }
  if (tid < 256) {
    int w = tid >> 5, col = (tid & 31) * 4;
    *reinterpret_cast<uint4*>(&mbs[w * 128 + col]) =
        *reinterpret_cast<const uint4*>(&mbg[(size_t)bt * 2048 + w * 256 + jbase + col]);
  }
  if (tid >= 384 && tid < 448) a2sv[tid - 384] = a2s[tid - 384];
  else if (tid >= 448) a2dv[tid - 448] = a2d[tid - 448];
  __syncthreads();

  if (tid < 256) {
    const int n = tid;
    const unsigned sh = (n & 1) * 16;
    float s = 0.f;
#pragma unroll 8
    for (int d = 0; d < 64; ++d) {
      unsigned u = sm.hpT[d][n >> 1];
      s += __uint_as_float((u >> sh) << 16) * a2sv[d];
    }
    ess[n] = s * LOG2E;
  } else if (tid < 384) {
    const int jl = tid - 256;
    const int n = jbase + jl;
    const unsigned sh = (n & 1) * 16;
    float s = 0.f;
#pragma unroll 8
    for (int d = 0; d < 64; ++d) {
      unsigned u = sm.hpT[d][n >> 1];
      s += __uint_as_float((u >> sh) << 16) * a2dv[d];
    }
    eds[jl] = s * LOG2E;
  }
  __syncthreads();

  const int lane = tid & 63, wv = tid >> 6;
  const int m = lane & 15, q = lane >> 4;
  const f32x4 z4 = {0.f, 0.f, 0.f, 0.f};
  f32x4 cacc[4], cden = z4;
#pragma unroll
  for (int nt = 0; nt < 4; ++nt) cacc[nt] = z4;
  const float edv = eds[wv * 16 + m];
  const short8 ones8 = {(short)0x3F80, (short)0x3F80, (short)0x3F80, (short)0x3F80,
                        (short)0x3F80, (short)0x3F80, (short)0x3F80, (short)0x3F80};

  for (int kt = 0; kt < 8; ++kt) {
    short8 bfr[4];
#pragma unroll
    for (int nt = 0; nt < 4; ++nt)
      bfr[nt] = *reinterpret_cast<const short8*>(&sm.hpT[nt * 16 + m][kt * 16 + q * 4]);
    float e[8];
    *reinterpret_cast<float4*>(&e[0]) = *reinterpret_cast<const float4*>(&ess[kt * 32 + q * 8]);
    *reinterpret_cast<float4*>(&e[4]) = *reinterpret_cast<const float4*>(&ess[kt * 32 + q * 8 + 4]);
    const unsigned bits = mbs[kt * 128 + wv * 16 + m] >> (q * 8);
    float pv[8];
#pragma unroll
    for (int r = 0; r < 8; ++r) {
      float sc = e[r] + edv;
      sc = fmaxf(sc, 0.2f * sc);
      pv[r] = ((bits >> r) & 1u) ? exp2f(sc) : 0.f;
    }
    union { unsigned u[4]; short8 s; } A;
#pragma unroll
    for (int h = 0; h < 4; ++h) A.u[h] = pack_bf16x2(pv[2 * h], pv[2 * h + 1]);
#pragma unroll
    for (int nt = 0; nt < 4; ++nt)
      cacc[nt] = __builtin_amdgcn_mfma_f32_16x16x32_bf16(A.s, bfr[nt], cacc[nt], 0, 0, 0);
    cden = __builtin_amdgcn_mfma_f32_16x16x32_bf16(A.s, ones8, cden, 0, 0, 0);
  }
  __syncthreads();

  float b2v[4];
#pragma unroll
  for (int nt = 0; nt < 4; ++nt) b2v[nt] = b2[nt * 16 + m];
#pragma unroll
  for (int reg = 0; reg < 4; ++reg) {
    const int jl = wv * 16 + q * 4 + reg;
    const float inv = 1.f / fmaxf(cden[reg], 1e-30f);
#pragma unroll
    for (int nt = 0; nt < 4; ++nt)
      sm.ob[jl][nt * 16 + m] = bf16_rn(cacc[nt][reg] * inv + b2v[nt]);
  }
  __syncthreads();

  // phase 2: out = od @ Wout[0:64] + spW + tW
  f32x4 c2[4];
#pragma unroll
  for (int ct = 0; ct < 4; ++ct) c2[ct] = z4;
#pragma unroll
  for (int kt2 = 0; kt2 < 2; ++kt2) {
    short8 a2f = *reinterpret_cast<const short8*>(&sm.ob[wv * 16 + m][kt2 * 32 + q * 8]);
#pragma unroll
    for (int ct = 0; ct < 4; ++ct) {
      short8 bw = *reinterpret_cast<const short8*>(&wol[ct * 16 + m][kt2 * 16 + q * 4]);
      c2[ct] = __builtin_amdgcn_mfma_f32_16x16x32_bf16(a2f, bw, c2[ct], 0, 0, 0);
    }
  }
  float tWv[4];
#pragma unroll
  for (int ct = 0; ct < 4; ++ct) tWv[ct] = tW[bt * 64 + ct * 16 + m];
#pragma unroll
  for (int reg = 0; reg < 4; ++reg) {
    const int j = jbase + wv * 16 + q * 4 + reg;
#pragma unroll
    for (int ct = 0; ct < 4; ++ct) {
      const int cc = ct * 16 + m;
      out[((size_t)bt * NNODE + j) * 64 + cc] =
          c2[ct][reg] + spW[j * 64 + cc] + tWv[ct];
    }
  }
}

// ---------------------------------------------------------------------------
extern "C" void kernel_launch(void* const* d_in, const int* in_sizes, int n_in,
                              void* d_out, int out_size, void* d_ws, size_t ws_size,
                              hipStream_t stream) {
  const float* x    = (const float*)d_in[0];
  const int*   adj  = (const int*)d_in[1];
  const float* te   = (const float*)d_in[2];
  const float* se   = (const float*)d_in[3];
  const float* pe   = (const float*)d_in[4];
  const float* Wt   = (const float*)d_in[5];
  const float* bt_  = (const float*)d_in[6];
  const float* Ws   = (const float*)d_in[7];
  const float* bs_  = (const float*)d_in[8];
  const float* Wp   = (const float*)d_in[9];
  const float* bp_  = (const float*)d_in[10];
  const float* Wfc  = (const float*)d_in[11];
  const float* bfc  = (const float*)d_in[12];
  const float* Wout = (const float*)d_in[13];
  const float* bout = (const float*)d_in[14];
  const float* W1   = (const float*)d_in[15];
  const float* b1   = (const float*)d_in[16];
  const float* a1s  = (const float*)d_in[17];
  const float* a1d  = (const float*)d_in[18];
  const float* W2   = (const float*)d_in[19];
  const float* b2   = (const float*)d_in[20];
  const float* a2s  = (const float*)d_in[21];
  const float* a2d  = (const float*)d_in[22];

  // workspace layout (26,116,096 B)
  char* ws = (char*)d_ws;
  unsigned*       mb   = (unsigned*)(ws);                  // 786432
  float*          tW   = (float*)(ws + 786432);            // 24576
  float*          spW  = (float*)(ws + 811008);            // 65536
  unsigned short* WoT  = (unsigned short*)(ws + 876544);   // 8192
  unsigned short* W1T  = (unsigned short*)(ws + 884736);   // 32768
  unsigned short* W2T  = (unsigned short*)(ws + 917504);   // 32768
  unsigned short* hpT  = (unsigned short*)(ws + 950272);   // 12582912 (hpT1, later hpT2)
  unsigned*       hgl  = (unsigned*)(ws + 13533184);       // 12582912

  pack_mask_kernel<<<dim3(NBT, 8), 256, 0, stream>>>(adj, mb);
  embed_kernel<<<NBT + NNODE, 64, 0, stream>>>(te, se, pe, Wt, bt_, Ws, bs_,
                                               Wp, bp_, Wfc, bfc, Wout, bout, tW, spW);
  prep_kernel<<<2, 256, 0, stream>>>(Wout, W1, W2, WoT, W1T, W2T);
  feat1_kernel<<<dim3(4, NBT), 256, 0, stream>>>(x, (const unsigned*)W1T, hpT);
  agg1_kernel<<<dim3(NBT, 4), 512, 0, stream>>>((const unsigned*)hpT, mb, a1s, a1d,
                                                b1, hgl);
  feat2_kernel<<<dim3(NBT, 4), 256, 0, stream>>>(hgl, (const unsigned*)W2T, hpT);
  agg2_kernel<<<dim3(NBT, 2), 512, 0, stream>>>((const unsigned*)hpT, mb, a2s, a2d,
                                                b2, (const unsigned*)WoT, spW, tW,
                                                (float*)d_out);
}

// Round 10
// 168.573 us; speedup vs baseline: 4.0871x; 1.0857x over previous
//
#include <hip/hip_runtime.h>
#include <hip/hip_bf16.h>
#include <cstdint>

#define NNODE 256
#define NBT   96
#define LOG2E 1.4426950408889634f

typedef __attribute__((ext_vector_type(8))) short short8;
typedef __attribute__((ext_vector_type(4))) float f32x4;

__device__ __forceinline__ unsigned pack_bf16x2(float a, float b) {
  unsigned ua = __float_as_uint(a);
  unsigned ub = __float_as_uint(b);
  unsigned ra = (ua + 0x7FFFu + ((ua >> 16) & 1u)) >> 16;
  unsigned rb = ((ub + 0x7FFFu + ((ub >> 16) & 1u)) >> 16) << 16;
  return ra | rb;
}
__device__ __forceinline__ unsigned short bf16_rn(float a) {
  unsigned ua = __float_as_uint(a);
  return (unsigned short)((ua + 0x7FFFu + ((ua >> 16) & 1u)) >> 16);
}

// ---------------------------------------------------------------------------
// Kernel 1: bit-pack adjacency, layout [bt][w][j]. bit b = adj[bt][32w+b][j]!=0
// ---------------------------------------------------------------------------
__global__ __launch_bounds__(256) void pack_mask_kernel(const int* __restrict__ adj,
                                                        unsigned* __restrict__ mb) {
  const int bt = blockIdx.x, w = blockIdx.y, j = threadIdx.x;
  const int* a = adj + (size_t)bt * NNODE * NNODE + (size_t)w * 32 * NNODE;
  unsigned v = 0;
#pragma unroll
  for (int b = 0; b < 32; ++b)
    v |= (a[b * NNODE + j] != 0 ? 1u : 0u) << b;
  mb[((size_t)bt * 8 + w) * 256 + j] = v;
}

// ---------------------------------------------------------------------------
// Kernel 2: small embedding chains (unchanged — verified).
// ---------------------------------------------------------------------------
__global__ __launch_bounds__(64) void embed_kernel(
    const float* __restrict__ te, const float* __restrict__ se, const float* __restrict__ pe,
    const float* __restrict__ Wt, const float* __restrict__ bt_,
    const float* __restrict__ Ws, const float* __restrict__ bs_,
    const float* __restrict__ Wp, const float* __restrict__ bp_,
    const float* __restrict__ Wfc, const float* __restrict__ bfc,
    const float* __restrict__ Wout, const float* __restrict__ bout,
    float* __restrict__ tW, float* __restrict__ spW) {
  const int j = threadIdx.x;
  __shared__ float A[64], Bv[64], C[64], D[64];
  const int blk = blockIdx.x;
  if (blk < NBT) {
    const int row = blk;
    float h = bt_[j];
    for (int k = 0; k < 32; ++k) h += te[row * 32 + k] * Wt[k * 64 + j];
    A[j] = h;
    __syncthreads();
    float tv = bfc[j];
    for (int k = 0; k < 64; ++k) tv += A[k] * Wfc[k * 64 + j];
    Bv[j] = tv;
    __syncthreads();
    float tw = bout[j];
    for (int d = 0; d < 64; ++d) tw += Bv[d] * Wout[(64 + d) * 64 + j];
    tW[row * 64 + j] = tw;
  } else {
    const int n = blk - NBT;
    float sh = bs_[j], ph = bp_[j];
    for (int k = 0; k < 32; ++k) {
      sh += se[n * 32 + k] * Ws[k * 64 + j];
      ph += pe[n * 32 + k] * Wp[k * 64 + j];
    }
    A[j] = sh; Bv[j] = ph;
    __syncthreads();
    float sv = bfc[j], pv = bfc[j];
    for (int k = 0; k < 64; ++k) {
      sv += A[k] * Wfc[k * 64 + j];
      pv += Bv[k] * Wfc[k * 64 + j];
    }
    C[j] = sv; D[j] = pv;
    __syncthreads();
    float spv = bout[j];
    for (int k = 0; k < 64; ++k)
      spv += C[k] * Wout[k * 64 + j] + D[k] * Wout[(64 + k) * 64 + j];
    __syncthreads();
    A[j] = spv;
    __syncthreads();
    float spw = 0.f;
    for (int d = 0; d < 64; ++d) spw += A[d] * Wout[(64 + d) * 64 + j];
    spW[n * 64 + j] = spw;
  }
}

// ---------------------------------------------------------------------------
// Kernel 2b: prep transposed bf16 weights (unchanged from round 7 — verified).
// ---------------------------------------------------------------------------
__global__ __launch_bounds__(256) void prep_kernel(
    const float* __restrict__ Wout, const float* __restrict__ W1,
    const float* __restrict__ W2, unsigned short* __restrict__ WoT,
    unsigned short* __restrict__ W1T, unsigned short* __restrict__ W2T) {
  const int tid = threadIdx.x;
  if (blockIdx.x == 0) {
    {
      const int c = tid >> 2, d0 = (tid & 3) * 16;
#pragma unroll
      for (int i = 0; i < 16; ++i)
        WoT[c * 64 + d0 + i] = bf16_rn(Wout[(size_t)(d0 + i) * 64 + c]);
    }
    const int k = tid;
#pragma unroll
    for (int d = 0; d < 64; ++d)
      W2T[d * 256 + k] = bf16_rn(W2[(size_t)k * 64 + d]);
  } else {
    const int hd = tid;
    unsigned u[32];
#pragma unroll
    for (int p = 0; p < 32; ++p) {
      float a = W1[(size_t)(2 * p) * 256 + hd];
      float b = W1[(size_t)(2 * p + 1) * 256 + hd];
      u[p] = pack_bf16x2(a, b);
    }
    unsigned* o = (unsigned*)(W1T + (size_t)hd * 64);
#pragma unroll
    for (int p = 0; p < 8; ++p) {
      uint4 v;
      v.x = u[4 * p + 0]; v.y = u[4 * p + 1];
      v.z = u[4 * p + 2]; v.w = u[4 * p + 3];
      *reinterpret_cast<uint4*>(o + 4 * p) = v;
    }
  }
}

// ---------------------------------------------------------------------------
// Kernel 3: fused feat1+agg1. grid (96, 4 heads, 2 j-halves), 512 thr.
// In-block: hp = x@W1slice via MFMA -> hpT in LDS -> es/ed -> masked-softmax
// MFMA aggregation for this j-half -> elu -> hgl.
// Eliminates the hpT1 global round-trip and one launch.
// ---------------------------------------------------------------------------
__global__ __launch_bounds__(512, 2) void fused1_kernel(
    const float* __restrict__ x, const unsigned* __restrict__ W1Tu,
    const unsigned* __restrict__ mbg, const float* __restrict__ a1s,
    const float* __restrict__ a1d, const float* __restrict__ b1,
    unsigned* __restrict__ hgl) {
  const int bt = blockIdx.x, head = blockIdx.y, z = blockIdx.z, tid = threadIdx.x;
  __shared__ union U {
    unsigned xb[256][36];          // feat B operand (36864 B)
    unsigned hpT[64][132];         // hp[d][n] bf16 (33792 B)
    unsigned short ob[128][72];    // output staging (18432 B)
  } sm;
  __shared__ unsigned w1t[64][36];
  __shared__ unsigned mbs[1024];   // 8 w-words x 128 j (this half)
  __shared__ float ess[256], eds[128], asv[64], adv[64];

  // ---- stage: x rows (t<256), W1T slice + attn vecs (t>=256), mask (t<256) ----
  if (tid < 256) {
    const float* xrow = x + ((size_t)bt * NNODE + tid) * 64;
    unsigned u[32];
#pragma unroll
    for (int p = 0; p < 16; ++p) {
      float4 v = reinterpret_cast<const float4*>(xrow)[p];
      u[2 * p] = pack_bf16x2(v.x, v.y);
      u[2 * p + 1] = pack_bf16x2(v.z, v.w);
    }
#pragma unroll
    for (int p = 0; p < 8; ++p) {
      uint4 v; v.x = u[4 * p]; v.y = u[4 * p + 1]; v.z = u[4 * p + 2]; v.w = u[4 * p + 3];
      *reinterpret_cast<uint4*>(&sm.xb[tid][4 * p]) = v;
    }
    const int w = tid >> 5, col = (tid & 31) * 4;
    *reinterpret_cast<uint4*>(&mbs[w * 128 + col]) =
        *reinterpret_cast<const uint4*>(&mbg[(size_t)bt * 2048 + w * 256 + z * 128 + col]);
  } else {
    const int tt = tid - 256;
#pragma unroll
    for (int c = 0; c < 2; ++c) {
      const int idx = tt * 2 + c;              // 0..511 -> 64 rows x 8 uint4
      const int r = idx >> 3, c4 = (idx & 7) * 4;
      *reinterpret_cast<uint4*>(&w1t[r][c4]) =
          *reinterpret_cast<const uint4*>(&W1Tu[(size_t)(head * 64 + r) * 32 + c4]);
    }
    if (tt < 64) asv[tt] = a1s[head * 64 + tt];
    else if (tt < 128) adv[tt - 64] = a1d[head * 64 + (tt - 64)];
  }
  __syncthreads();

  const int lane = tid & 63, wv = tid >> 6;
  const int m = lane & 15, q = lane >> 4;
  const f32x4 z4 = {0.f, 0.f, 0.f, 0.f};

  // ---- feat MFMA: hp[d][n], wave wv covers n in [wv*32, wv*32+32) ----
  f32x4 cf[4][2];
#pragma unroll
  for (int mt = 0; mt < 4; ++mt)
#pragma unroll
    for (int nt = 0; nt < 2; ++nt) cf[mt][nt] = z4;
#pragma unroll
  for (int kt = 0; kt < 2; ++kt) {
    short8 af[4], bf[2];
#pragma unroll
    for (int mt = 0; mt < 4; ++mt)
      af[mt] = *reinterpret_cast<const short8*>(&w1t[mt * 16 + m][kt * 16 + q * 4]);
#pragma unroll
    for (int nt = 0; nt < 2; ++nt)
      bf[nt] = *reinterpret_cast<const short8*>(&sm.xb[wv * 32 + nt * 16 + m][kt * 16 + q * 4]);
#pragma unroll
    for (int mt = 0; mt < 4; ++mt)
#pragma unroll
      for (int nt = 0; nt < 2; ++nt)
        cf[mt][nt] = __builtin_amdgcn_mfma_f32_16x16x32_bf16(af[mt], bf[nt], cf[mt][nt], 0, 0, 0);
  }
  __syncthreads();   // xb dead; hpT overlay safe

  {
    unsigned short* hpT16 = reinterpret_cast<unsigned short*>(&sm.hpT[0][0]); // [64][264]
#pragma unroll
    for (int mt = 0; mt < 4; ++mt)
#pragma unroll
      for (int nt = 0; nt < 2; ++nt)
#pragma unroll
        for (int reg = 0; reg < 4; ++reg) {
          const int d = mt * 16 + q * 4 + reg;
          const int n = wv * 32 + nt * 16 + m;
          hpT16[d * 264 + n] = bf16_rn(cf[mt][nt][reg]);
        }
  }
  __syncthreads();

  // ---- es (all 256 i) / ed (this half's 128 j) from bf16 hpT ----
  if (tid < 256) {
    const int n = tid;
    const unsigned sh = (n & 1) * 16;
    float s = 0.f;
#pragma unroll 8
    for (int d = 0; d < 64; ++d) {
      unsigned u = sm.hpT[d][n >> 1];
      s += __uint_as_float((u >> sh) << 16) * asv[d];
    }
    ess[n] = s * LOG2E;
  } else if (tid < 384) {
    const int jl = tid - 256;
    const int n = z * 128 + jl;
    const unsigned sh = (n & 1) * 16;
    float s = 0.f;
#pragma unroll 8
    for (int d = 0; d < 64; ++d) {
      unsigned u = sm.hpT[d][n >> 1];
      s += __uint_as_float((u >> sh) << 16) * adv[d];
    }
    eds[jl] = s * LOG2E;
  }
  __syncthreads();

  // ---- agg: wave owns 16 j-rows (jl = wv*16 + ...) ----
  f32x4 cacc[4], cden = z4;
#pragma unroll
  for (int nt = 0; nt < 4; ++nt) cacc[nt] = z4;
  const float edv = eds[wv * 16 + m];
  const short8 ones8 = {(short)0x3F80, (short)0x3F80, (short)0x3F80, (short)0x3F80,
                        (short)0x3F80, (short)0x3F80, (short)0x3F80, (short)0x3F80};

  for (int kt = 0; kt < 8; ++kt) {
    short8 bfr[4];
#pragma unroll
    for (int nt = 0; nt < 4; ++nt)
      bfr[nt] = *reinterpret_cast<const short8*>(&sm.hpT[nt * 16 + m][kt * 16 + q * 4]);
    float e[8];
    *reinterpret_cast<float4*>(&e[0]) = *reinterpret_cast<const float4*>(&ess[kt * 32 + q * 8]);
    *reinterpret_cast<float4*>(&e[4]) = *reinterpret_cast<const float4*>(&ess[kt * 32 + q * 8 + 4]);
    const unsigned bits = mbs[kt * 128 + wv * 16 + m] >> (q * 8);
    float pv[8];
#pragma unroll
    for (int r = 0; r < 8; ++r) {
      float sc = e[r] + edv;
      sc = fmaxf(sc, 0.2f * sc);
      pv[r] = ((bits >> r) & 1u) ? exp2f(sc) : 0.f;
    }
    union { unsigned u[4]; short8 s; } A;
#pragma unroll
    for (int h = 0; h < 4; ++h) A.u[h] = pack_bf16x2(pv[2 * h], pv[2 * h + 1]);
#pragma unroll
    for (int nt = 0; nt < 4; ++nt)
      cacc[nt] = __builtin_amdgcn_mfma_f32_16x16x32_bf16(A.s, bfr[nt], cacc[nt], 0, 0, 0);
    cden = __builtin_amdgcn_mfma_f32_16x16x32_bf16(A.s, ones8, cden, 0, 0, 0);
  }
  __syncthreads();   // hpT dead; ob overlay safe

  float b1v[4];
#pragma unroll
  for (int nt = 0; nt < 4; ++nt) b1v[nt] = b1[head * 64 + nt * 16 + m];
#pragma unroll
  for (int reg = 0; reg < 4; ++reg) {
    const int jl = wv * 16 + q * 4 + reg;
    const float inv = 1.f / fmaxf(cden[reg], 1e-30f);
#pragma unroll
    for (int nt = 0; nt < 4; ++nt) {
      float v = cacc[nt][reg] * inv + b1v[nt];
      v = v > 0.f ? v : expm1f(v);
      sm.ob[jl][nt * 16 + m] = bf16_rn(v);
    }
  }
  __syncthreads();

  // ---- global write: 128 rows x 32 uints = 1024 uint4, 2 per thread ----
  unsigned* go = hgl + (size_t)bt * 32768 + (size_t)z * 128 * 128 + head * 32;
#pragma unroll
  for (int c = 0; c < 2; ++c) {
    const int idx = tid * 2 + c;             // 0..1023
    const int jl = idx >> 3, c4 = (idx & 7) * 4;
    *reinterpret_cast<uint4*>(&go[(size_t)jl * 128 + c4]) =
        *reinterpret_cast<const uint4*>(&sm.ob[jl][c4 * 2]);
  }
}

// ---------------------------------------------------------------------------
// Kernel 4: feat2 (MFMA) — hpT2[bt][d][n] = (h @ W2)[n][d], K=256 (unchanged).
// ---------------------------------------------------------------------------
__global__ __launch_bounds__(256, 2) void feat2_kernel(
    const unsigned* __restrict__ hglu, const unsigned* __restrict__ W2Tu,
    unsigned short* __restrict__ hpT2) {
  const int bt = blockIdx.x, ng = blockIdx.y, tid = threadIdx.x;
  __shared__ unsigned hb[64][132];
  __shared__ unsigned w2t[64][132];

#pragma unroll
  for (int c = 0; c < 8; ++c) {
    int i4 = tid + c * 256;
    int row = i4 >> 5, col = (i4 & 31) << 2;
    *reinterpret_cast<uint4*>(&hb[row][col]) =
        *reinterpret_cast<const uint4*>(&hglu[((size_t)bt * 256 + ng * 64 + row) * 128 + col]);
    *reinterpret_cast<uint4*>(&w2t[row][col]) =
        *reinterpret_cast<const uint4*>(&W2Tu[row * 128 + col]);
  }
  __syncthreads();

  const int lane = tid & 63, wv = tid >> 6;
  const int m = lane & 15, q = lane >> 4;
  const f32x4 z4 = {0.f, 0.f, 0.f, 0.f};
  f32x4 cf[4];
#pragma unroll
  for (int mt = 0; mt < 4; ++mt) cf[mt] = z4;

  for (int kt = 0; kt < 8; ++kt) {
    short8 bf = *reinterpret_cast<const short8*>(&hb[wv * 16 + m][kt * 16 + q * 4]);
#pragma unroll
    for (int mt = 0; mt < 4; ++mt) {
      short8 af = *reinterpret_cast<const short8*>(&w2t[mt * 16 + m][kt * 16 + q * 4]);
      cf[mt] = __builtin_amdgcn_mfma_f32_16x16x32_bf16(af, bf, cf[mt], 0, 0, 0);
    }
  }

  unsigned short* go = hpT2 + (size_t)bt * 16384;
#pragma unroll
  for (int mt = 0; mt < 4; ++mt)
#pragma unroll
    for (int reg = 0; reg < 4; ++reg) {
      const int d = mt * 16 + q * 4 + reg;
      const int n = ng * 64 + wv * 16 + m;
      go[d * 256 + n] = bf16_rn(cf[mt][reg]);
    }
}

// ---------------------------------------------------------------------------
// Kernel 5: agg2 — MFMA aggregation + fused od@Wout + spW + tW (unchanged).
// ---------------------------------------------------------------------------
__global__ __launch_bounds__(512, 2) void agg2_kernel(
    const unsigned* __restrict__ hpT2u, const unsigned* __restrict__ mbg,
    const float* __restrict__ a2s, const float* __restrict__ a2d,
    const float* __restrict__ b2, const unsigned* __restrict__ WoTu,
    const float* __restrict__ spW, const float* __restrict__ tW,
    float* __restrict__ out) {
  const int bt = blockIdx.x, jh = blockIdx.y, tid = threadIdx.x;
  const int jbase = jh * 128;
  __shared__ union U2 {
    unsigned hpT[64][132];
    unsigned short ob[128][72];
  } sm;
  __shared__ unsigned wol[64][36];
  __shared__ unsigned mbs[8 * 128];
  __shared__ float ess[256], eds[128];
  __shared__ float a2sv[64], a2dv[64];

  const unsigned* gh = hpT2u + (size_t)bt * 8192;
#pragma unroll
  for (int c = 0; c < 4; ++c) {
    int i4 = tid + c * 512;
    int row = i4 >> 5, col = (i4 & 31) << 2;
    *reinterpret_cast<uint4*>(&sm.hpT[row][col]) =
        *reinterpret_cast<const uint4*>(&gh[row * 128 + col]);
  }
  {
    int row = tid >> 3, col = (tid & 7) * 4;
    *reinterpret_cast<uint4*>(&wol[row][col]) =
        *reinterpret_cast<const uint4*>(&WoTu[row * 32 + col]);
  }
  if (tid < 256) {
    int w = tid >> 5, col = (tid & 31) * 4;
    *reinterpret_cast<uint4*>(&mbs[w * 128 + col]) =
        *reinterpret_cast<const uint4*>(&mbg[(size_t)bt * 2048 + w * 256 + jbase + col]);
  }
  if (tid >= 384 && tid < 448) a2sv[tid - 384] = a2s[tid - 384];
  else if (tid >= 448) a2dv[tid - 448] = a2d[tid - 448];
  __syncthreads();

  if (tid < 256) {
    const int n = tid;
    const unsigned sh = (n & 1) * 16;
    float s = 0.f;
#pragma unroll 8
    for (int d = 0; d < 64; ++d) {
      unsigned u = sm.hpT[d][n >> 1];
      s += __uint_as_float((u >> sh) << 16) * a2sv[d];
    }
    ess[n] = s * LOG2E;
  } else if (tid < 384) {
    const int jl = tid - 256;
    const int n = jbase + jl;
    const unsigned sh = (n & 1) * 16;
    float s = 0.f;
#pragma unroll 8
    for (int d = 0; d < 64; ++d) {
      unsigned u = sm.hpT[d][n >> 1];
      s += __uint_as_float((u >> sh) << 16) * a2dv[d];
    }
    eds[jl] = s * LOG2E;
  }
  __syncthreads();

  const int lane = tid & 63, wv = tid >> 6;
  const int m = lane & 15, q = lane >> 4;
  const f32x4 z4 = {0.f, 0.f, 0.f, 0.f};
  f32x4 cacc[4], cden = z4;
#pragma unroll
  for (int nt = 0; nt < 4; ++nt) cacc[nt] = z4;
  const float edv = eds[wv * 16 + m];
  const short8 ones8 = {(short)0x3F80, (short)0x3F80, (short)0x3F80, (short)0x3F80,
                        (short)0x3F80, (short)0x3F80, (short)0x3F80, (short)0x3F80};

  for (int kt = 0; kt < 8; ++kt) {
    short8 bfr[4];
#pragma unroll
    for (int nt = 0; nt < 4; ++nt)
      bfr[nt] = *reinterpret_cast<const short8*>(&sm.hpT[nt * 16 + m][kt * 16 + q * 4]);
    float e[8];
    *reinterpret_cast<float4*>(&e[0]) = *reinterpret_cast<const float4*>(&ess[kt * 32 + q * 8]);
    *reinterpret_cast<float4*>(&e[4]) = *reinterpret_cast<const float4*>(&ess[kt * 32 + q * 8 + 4]);
    const unsigned bits = mbs[kt * 128 + wv * 16 + m] >> (q * 8);
    float pv[8];
#pragma unroll
    for (int r = 0; r < 8; ++r) {
      float sc = e[r] + edv;
      sc = fmaxf(sc, 0.2f * sc);
      pv[r] = ((bits >> r) & 1u) ? exp2f(sc) : 0.f;
    }
    union { unsigned u[4]; short8 s; } A;
#pragma unroll
    for (int h = 0; h < 4; ++h) A.u[h] = pack_bf16x2(pv[2 * h], pv[2 * h + 1]);
#pragma unroll
    for (int nt = 0; nt < 4; ++nt)
      cacc[nt] = __builtin_amdgcn_mfma_f32_16x16x32_bf16(A.s, bfr[nt], cacc[nt], 0, 0, 0);
    cden = __builtin_amdgcn_mfma_f32_16x16x32_bf16(A.s, ones8, cden, 0, 0, 0);
  }
  __syncthreads();

  float b2v[4];
#pragma unroll
  for (int nt = 0; nt < 4; ++nt) b2v[nt] = b2[nt * 16 + m];
#pragma unroll
  for (int reg = 0; reg < 4; ++reg) {
    const int jl = wv * 16 + q * 4 + reg;
    const float inv = 1.f / fmaxf(cden[reg], 1e-30f);
#pragma unroll
    for (int nt = 0; nt < 4; ++nt)
      sm.ob[jl][nt * 16 + m] = bf16_rn(cacc[nt][reg] * inv + b2v[nt]);
  }
  __syncthreads();

  f32x4 c2[4];
#pragma unroll
  for (int ct = 0; ct < 4; ++ct) c2[ct] = z4;
#pragma unroll
  for (int kt2 = 0; kt2 < 2; ++kt2) {
    short8 a2f = *reinterpret_cast<const short8*>(&sm.ob[wv * 16 + m][kt2 * 32 + q * 8]);
#pragma unroll
    for (int ct = 0; ct < 4; ++ct) {
      short8 bw = *reinterpret_cast<const short8*>(&wol[ct * 16 + m][kt2 * 16 + q * 4]);
      c2[ct] = __builtin_amdgcn_mfma_f32_16x16x32_bf16(a2f, bw, c2[ct], 0, 0, 0);
    }
  }
  float tWv[4];
#pragma unroll
  for (int ct = 0; ct < 4; ++ct) tWv[ct] = tW[bt * 64 + ct * 16 + m];
#pragma unroll
  for (int reg = 0; reg < 4; ++reg) {
    const int j = jbase + wv * 16 + q * 4 + reg;
#pragma unroll
    for (int ct = 0; ct < 4; ++ct) {
      const int cc = ct * 16 + m;
      out[((size_t)bt * NNODE + j) * 64 + cc] =
          c2[ct][reg] + spW[j * 64 + cc] + tWv[ct];
    }
  }
}

// ---------------------------------------------------------------------------
extern "C" void kernel_launch(void* const* d_in, const int* in_sizes, int n_in,
                              void* d_out, int out_size, void* d_ws, size_t ws_size,
                              hipStream_t stream) {
  const float* x    = (const float*)d_in[0];
  const int*   adj  = (const int*)d_in[1];
  const float* te   = (const float*)d_in[2];
  const float* se   = (const float*)d_in[3];
  const float* pe   = (const float*)d_in[4];
  const float* Wt   = (const float*)d_in[5];
  const float* bt_  = (const float*)d_in[6];
  const float* Ws   = (const float*)d_in[7];
  const float* bs_  = (const float*)d_in[8];
  const float* Wp   = (const float*)d_in[9];
  const float* bp_  = (const float*)d_in[10];
  const float* Wfc  = (const float*)d_in[11];
  const float* bfc  = (const float*)d_in[12];
  const float* Wout = (const float*)d_in[13];
  const float* bout = (const float*)d_in[14];
  const float* W1   = (const float*)d_in[15];
  const float* b1   = (const float*)d_in[16];
  const float* a1s  = (const float*)d_in[17];
  const float* a1d  = (const float*)d_in[18];
  const float* W2   = (const float*)d_in[19];
  const float* b2   = (const float*)d_in[20];
  const float* a2s  = (const float*)d_in[21];
  const float* a2d  = (const float*)d_in[22];

  // workspace layout (same offsets as round 7; hpT now only feat2->agg2)
  char* ws = (char*)d_ws;
  unsigned*       mb   = (unsigned*)(ws);                  // 786432
  float*          tW   = (float*)(ws + 786432);            // 24576
  float*          spW  = (float*)(ws + 811008);            // 65536
  unsigned short* WoT  = (unsigned short*)(ws + 876544);   // 8192
  unsigned short* W1T  = (unsigned short*)(ws + 884736);   // 32768
  unsigned short* W2T  = (unsigned short*)(ws + 917504);   // 32768
  unsigned short* hpT  = (unsigned short*)(ws + 950272);   // (hpT2 only)
  unsigned*       hgl  = (unsigned*)(ws + 13533184);       // 12582912

  pack_mask_kernel<<<dim3(NBT, 8), 256, 0, stream>>>(adj, mb);
  embed_kernel<<<NBT + NNODE, 64, 0, stream>>>(te, se, pe, Wt, bt_, Ws, bs_,
                                               Wp, bp_, Wfc, bfc, Wout, bout, tW, spW);
  prep_kernel<<<2, 256, 0, stream>>>(Wout, W1, W2, WoT, W1T, W2T);
  fused1_kernel<<<dim3(NBT, 4, 2), 512, 0, stream>>>(x, (const unsigned*)W1T, mb,
                                                     a1s, a1d, b1, hgl);
  feat2_kernel<<<dim3(NBT, 4), 256, 0, stream>>>(hgl, (const unsigned*)W2T, hpT);
  agg2_kernel<<<dim3(NBT, 2), 512, 0, stream>>>((const unsigned*)hpT, mb, a2s, a2d,
                                                b2, (const unsigned*)WoT, spW, tW,
                                                (float*)d_out);
}